// Round 3
// baseline (784.479 us; speedup 1.0000x reference)
//
#include <hip/hip_runtime.h>
#include <hip/hip_bf16.h>
#include <cstdint>

// ---------- bf16 helpers (raw ushort representation) ----------
__device__ __forceinline__ unsigned short f2b(float f) {
    union { float f; unsigned int i; } v; v.f = f;
    unsigned int i = v.i;
    unsigned int r = (i + 0x7FFFu + ((i >> 16) & 1u)) >> 16;   // RNE, finite inputs
    return (unsigned short)r;
}
__device__ __forceinline__ float b2f_lo(unsigned int p) {
    union { unsigned int i; float f; } v; v.i = p << 16; return v.f;
}
__device__ __forceinline__ float b2f_hi(unsigned int p) {
    union { unsigned int i; float f; } v; v.i = p & 0xFFFF0000u; return v.f;
}
__device__ __forceinline__ unsigned int pack2(float a, float b) {
    return (unsigned int)f2b(a) | ((unsigned int)f2b(b) << 16);
}

typedef __attribute__((__ext_vector_type__(8))) __bf16 bf16x8;
typedef __attribute__((__ext_vector_type__(4))) float  f32x4;

#define N_NODES 100000
#define N_EDGES 3200000
#define NBUCK   200        // coarse buckets
#define BSZ     500        // nodes per bucket (200*500 = 100000)

// ---------- 1. coarse histograms (dst and src) — LDS-privatized ----------
__global__ void k_hist2(const int* __restrict__ src, const int* __restrict__ dst,
                        int* __restrict__ gcntA, int* __restrict__ gcntB, int E) {
    __shared__ int hA[NBUCK], hB[NBUCK];
    int t = threadIdx.x;
    if (t < NBUCK) { hA[t] = 0; hB[t] = 0; }
    __syncthreads();
    for (int i = blockIdx.x * blockDim.x + t; i < E; i += gridDim.x * blockDim.x) {
        atomicAdd(&hA[dst[i] / BSZ], 1);
        atomicAdd(&hB[src[i] / BSZ], 1);
    }
    __syncthreads();
    if (t < NBUCK) {
        if (hA[t]) atomicAdd(&gcntA[t], hA[t]);
        if (hB[t]) atomicAdd(&gcntB[t], hB[t]);
    }
}

// ---------- 2. scan coarse counts -> bucket bases + cursors ----------
__global__ void k_scan_coarse(const int* __restrict__ gcntA, const int* __restrict__ gcntB,
                              int* __restrict__ gbaseA, int* __restrict__ gbaseB,
                              int* __restrict__ gcurA, int* __restrict__ gcurB,
                              int* __restrict__ offsets) {
    __shared__ int pA[256], pB[256];
    int t = threadIdx.x;
    int vA = (t < NBUCK) ? gcntA[t] : 0;
    int vB = (t < NBUCK) ? gcntB[t] : 0;
    pA[t] = vA; pB[t] = vB;
    __syncthreads();
    for (int d = 1; d < 256; d <<= 1) {
        int a = (t >= d) ? pA[t - d] : 0;
        int b = (t >= d) ? pB[t - d] : 0;
        __syncthreads();
        pA[t] += a; pB[t] += b;
        __syncthreads();
    }
    if (t < NBUCK) {
        gbaseA[t] = pA[t] - vA; gcurA[t] = pA[t] - vA;
        gbaseB[t] = pB[t] - vB; gcurB[t] = pB[t] - vB;
    }
    if (t == 255) {
        gbaseA[NBUCK] = pA[255];
        gbaseB[NBUCK] = pB[255];
        offsets[N_NODES] = pA[255];   // == E
    }
}

// ---------- 3. scatter: packed u32 (dloc<<17|src) by dst bucket; keys by src bucket ----------
__global__ void k_scatter(const int* __restrict__ src, const int* __restrict__ dst,
                          int* __restrict__ gcurA, int* __restrict__ gcurB,
                          unsigned* __restrict__ pairs, int* __restrict__ keysB, int E) {
    __shared__ int hA[NBUCK], hB[NBUCK], baA[NBUCK], baB[NBUCK], lcA[NBUCK], lcB[NBUCK];
    int t = threadIdx.x;
    const int CHUNK = 12500;                       // E / 256 blocks
    int lo = blockIdx.x * CHUNK, hi = min(lo + CHUNK, E);
    if (t < NBUCK) { hA[t] = 0; hB[t] = 0; }
    __syncthreads();
    for (int i = lo + t; i < hi; i += 256) {
        atomicAdd(&hA[dst[i] / BSZ], 1);
        atomicAdd(&hB[src[i] / BSZ], 1);
    }
    __syncthreads();
    if (t < NBUCK) {
        baA[t] = hA[t] ? atomicAdd(&gcurA[t], hA[t]) : 0;
        lcA[t] = 0;
        baB[t] = hB[t] ? atomicAdd(&gcurB[t], hB[t]) : 0;
        lcB[t] = 0;
    }
    __syncthreads();
    for (int i = lo + t; i < hi; i += 256) {
        int s = src[i], d = dst[i];
        int bA = d / BSZ;
        int l  = atomicAdd(&lcA[bA], 1);
        pairs[baA[bA] + l] = ((unsigned)(d - bA * BSZ) << 17) | (unsigned)s;
        int bB = s / BSZ;
        int l2 = atomicAdd(&lcB[bB], 1);
        keysB[baB[bB] + l2] = s;
    }
}

// ---------- 4. per-bucket CSR finalize: offsets, in_norm, esrc ----------
__global__ void k_csr_bucket(const unsigned* __restrict__ pairs, const int* __restrict__ gbaseA,
                             int* __restrict__ offsets, float* __restrict__ in_norm,
                             int* __restrict__ esrc) {
    __shared__ int hist[512], scan[512], curs[512];
    int b = blockIdx.x, t = threadIdx.x;
    int node0 = b * BSZ;
    int bstart = gbaseA[b], bend = gbaseA[b + 1];
    if (t < 512) hist[t] = 0;
    __syncthreads();
    for (int i = bstart + t; i < bend; i += 1024)
        atomicAdd(&hist[pairs[i] >> 17], 1);
    __syncthreads();
    if (t < 512) scan[t] = hist[t];
    __syncthreads();
    for (int d = 1; d < 512; d <<= 1) {
        int v = (t < 512 && t >= d) ? scan[t - d] : 0;
        __syncthreads();
        if (t < 512) scan[t] += v;
        __syncthreads();
    }
    if (t < BSZ) {
        int excl = scan[t] - hist[t];
        offsets[node0 + t] = bstart + excl;
        in_norm[node0 + t] = rsqrtf((float)max(hist[t], 1));
        curs[t] = excl;
    }
    __syncthreads();
    for (int i = bstart + t; i < bend; i += 1024) {
        unsigned p = pairs[i];
        int d = (int)(p >> 17);
        int l = atomicAdd(&curs[d], 1);
        esrc[bstart + l] = (int)(p & 0x1FFFFu);
    }
}

// ---------- 4b. canonicalize: wave-parallel bitonic sort of each segment ----------
__global__ void k_sortwave(const int* __restrict__ offsets, int* __restrict__ esrc, int N) {
    int node = blockIdx.x * 4 + (threadIdx.x >> 6);
    if (node >= N) return;
    int lane = threadIdx.x & 63;
    int lo = offsets[node], hi = offsets[node + 1];
    int len = hi - lo;
    if (len <= 1) return;
    const int INF = 0x7FFFFFFF;
    int v0 = (lane < len) ? esrc[lo + lane] : INF;
    int v1 = (64 + lane < len) ? esrc[lo + 64 + lane] : INF;
#pragma unroll
    for (int k = 2; k <= 128; k <<= 1) {
#pragma unroll
        for (int d = 64; d > 0; d >>= 1) {
            if (d >= k) continue;
            if (d == 64) {
                int a = min(v0, v1), b = max(v0, v1);
                v0 = a; v1 = b;
            } else {
                int w0 = __shfl_xor(v0, d, 64);
                int w1 = __shfl_xor(v1, d, 64);
                bool up0 = ((lane & k) == 0);
                bool up1 = (((64 + lane) & k) == 0);
                bool lower = ((lane & d) == 0);
                v0 = (lower == up0) ? min(v0, w0) : max(v0, w0);
                v1 = (lower == up1) ? min(v1, w1) : max(v1, w1);
            }
        }
    }
    if (lane < len) esrc[lo + lane] = v0;
    if (64 + lane < len) esrc[lo + 64 + lane] = v1;
}

// ---------- 5. fused: per-bucket src count -> out_norm + scale bucket's features ----------
__global__ void k_count_scale(const int* __restrict__ keys, const int* __restrict__ gbaseB,
                              const float4* __restrict__ x4, float* __restrict__ out_norm,
                              uint2* __restrict__ xs) {
    __shared__ int hist[512];
    __shared__ float onl[BSZ];
    int b = blockIdx.x, t = threadIdx.x;
    int node0 = b * BSZ;
    int bstart = gbaseB[b], bend = gbaseB[b + 1];
    if (t < 512) hist[t] = 0;
    __syncthreads();
    for (int i = bstart + t; i < bend; i += 1024)
        atomicAdd(&hist[keys[i] - node0], 1);
    __syncthreads();
    if (t < BSZ) {
        float on = rsqrtf((float)max(hist[t], 1));
        onl[t] = on;
        out_norm[node0 + t] = on;
    }
    __syncthreads();
    // scale this bucket's 500 x 128 features: xs = bf16(x * out_norm)
    size_t base4 = (size_t)node0 * 32;
    for (int i = t; i < BSZ * 32; i += 1024) {
        float on = onl[i >> 5];
        float4 v = x4[base4 + i];
        uint2 o;
        o.x = pack2(v.x * on, v.y * on);
        o.y = pack2(v.z * on, v.w * on);
        xs[base4 + i] = o;
    }
}

// ---------- 7. merged weight transpose + bf16 cast (all four weights) ----------
__global__ void k_transpose4(const float* __restrict__ w1, const float* __restrict__ w2,
                             const float* __restrict__ wm1, const float* __restrict__ wm2,
                             unsigned short* __restrict__ t1, unsigned short* __restrict__ t2,
                             unsigned short* __restrict__ tm1, unsigned short* __restrict__ tm2) {
    int i = blockIdx.x * blockDim.x + threadIdx.x;
    const float* w; unsigned short* t; int N, idx;
    if (i < 16384)       { w = w1;  t = t1;  N = 128; idx = i; }
    else if (i < 32768)  { w = w2;  t = t2;  N = 128; idx = i - 16384; }
    else if (i < 65536)  { w = wm1; t = tm1; N = 256; idx = i - 32768; }
    else if (i < 81920)  { w = wm2; t = tm2; N = 64;  idx = i - 65536; }
    else return;
    int K = (i < 65536) ? 128 : 256;
    int k = idx / N, n = idx - k * N;
    t[(size_t)n * K + k] = f2b(w[idx]);
}

// ---------- aggregate inner body: 8-row / 4-row / 1-row tiers, per-lane k-ascending ----------
// Per-lane summation order is strictly ascending k (identical to the verified 4-deep
// version) -> bit-identical results; the tiering only changes load concurrency.
#define AGG_ADD(p)                                                              \
        a0 += b2f_lo(p.x); a1 += b2f_hi(p.x);                                   \
        a2 += b2f_lo(p.y); a3 += b2f_hi(p.y);                                   \
        a4 += b2f_lo(p.z); a5 += b2f_hi(p.z);                                   \
        a6 += b2f_lo(p.w); a7 += b2f_hi(p.w);

#define AGG_NODE_BODY(node)                                                     \
    int lo = offsets[node], hi = offsets[node + 1];                             \
    float a0 = 0.f, a1 = 0.f, a2 = 0.f, a3 = 0.f,                               \
          a4 = 0.f, a5 = 0.f, a6 = 0.f, a7 = 0.f;                               \
    int k = lo + g;                                                             \
    for (; k + 28 < hi; k += 32) {                                              \
        int s0 = esrc[k];      int s1 = esrc[k + 4];                            \
        int s2 = esrc[k + 8];  int s3 = esrc[k + 12];                           \
        int s4 = esrc[k + 16]; int s5 = esrc[k + 20];                           \
        int s6 = esrc[k + 24]; int s7 = esrc[k + 28];                           \
        uint4 p0 = feat[(size_t)s0 * 16 + c];                                   \
        uint4 p1 = feat[(size_t)s1 * 16 + c];                                   \
        uint4 p2 = feat[(size_t)s2 * 16 + c];                                   \
        uint4 p3 = feat[(size_t)s3 * 16 + c];                                   \
        uint4 p4 = feat[(size_t)s4 * 16 + c];                                   \
        uint4 p5 = feat[(size_t)s5 * 16 + c];                                   \
        uint4 p6 = feat[(size_t)s6 * 16 + c];                                   \
        uint4 p7 = feat[(size_t)s7 * 16 + c];                                   \
        AGG_ADD(p0) AGG_ADD(p1) AGG_ADD(p2) AGG_ADD(p3)                         \
        AGG_ADD(p4) AGG_ADD(p5) AGG_ADD(p6) AGG_ADD(p7)                         \
    }                                                                           \
    for (; k + 12 < hi; k += 16) {                                              \
        int s0 = esrc[k];                                                       \
        int s1 = esrc[k + 4];                                                   \
        int s2 = esrc[k + 8];                                                   \
        int s3 = esrc[k + 12];                                                  \
        uint4 p0 = feat[(size_t)s0 * 16 + c];                                   \
        uint4 p1 = feat[(size_t)s1 * 16 + c];                                   \
        uint4 p2 = feat[(size_t)s2 * 16 + c];                                   \
        uint4 p3 = feat[(size_t)s3 * 16 + c];                                   \
        AGG_ADD(p0) AGG_ADD(p1) AGG_ADD(p2) AGG_ADD(p3)                         \
    }                                                                           \
    for (; k < hi; k += 4) {                                                    \
        int s = esrc[k];                                                        \
        uint4 p = feat[(size_t)s * 16 + c];                                     \
        AGG_ADD(p)                                                              \
    }                                                                           \
    a0 += __shfl_xor(a0, 16, 64); a0 += __shfl_xor(a0, 32, 64);                 \
    a1 += __shfl_xor(a1, 16, 64); a1 += __shfl_xor(a1, 32, 64);                 \
    a2 += __shfl_xor(a2, 16, 64); a2 += __shfl_xor(a2, 32, 64);                 \
    a3 += __shfl_xor(a3, 16, 64); a3 += __shfl_xor(a3, 32, 64);                 \
    a4 += __shfl_xor(a4, 16, 64); a4 += __shfl_xor(a4, 32, 64);                 \
    a5 += __shfl_xor(a5, 16, 64); a5 += __shfl_xor(a5, 32, 64);                 \
    a6 += __shfl_xor(a6, 16, 64); a6 += __shfl_xor(a6, 32, 64);                 \
    a7 += __shfl_xor(a7, 16, 64); a7 += __shfl_xor(a7, 32, 64);

// ---------- 8. fused conv1: aggregate(32 nodes) -> LDS -> MFMA GEMM -> relu*scale ----------
// LDS 8704 B, 4 waves/block -> 8 blocks/CU (wave-capped, 100% occupancy).
__global__ __launch_bounds__(256, 8)
void k_conv(const int* __restrict__ offsets, const int* __restrict__ esrc,
            const uint4* __restrict__ feat, const float* __restrict__ in_norm,
            const unsigned short* __restrict__ WT, const float* __restrict__ bias,
            const float* __restrict__ row_scale, unsigned short* __restrict__ C,
            int N) {
    __shared__ unsigned short A[32][136];       // 272B row stride, 16B-aligned rows
    int wv = threadIdx.x >> 6, lane = threadIdx.x & 63;
    int row0 = blockIdx.x * 32;
    int g = lane >> 4, c = lane & 15;

    // phase A: aggregate
    for (int i = 0; i < 8; ++i) {
        int nl = wv * 8 + i;
        int node = row0 + nl;
        AGG_NODE_BODY(node)
        if (g == 0) {
            float inn = in_norm[node];
            uint4 o;
            o.x = pack2(a0 * inn, a1 * inn);
            o.y = pack2(a2 * inn, a3 * inn);
            o.z = pack2(a4 * inn, a5 * inn);
            o.w = pack2(a6 * inn, a7 * inn);
            *(uint4*)&A[nl][c * 8] = o;
        }
    }
    __syncthreads();

    // phase B: GEMM 32x128 tile, wave covers cols wv*32 .. wv*32+31
    int m = lane & 15, q = lane >> 4;
    const unsigned short* b0 = WT + (size_t)(wv * 32 + m) * 128 + q * 8;
    const unsigned short* b1 = b0 + (size_t)16 * 128;
    f32x4 acc00 = {0.f, 0.f, 0.f, 0.f}, acc10 = {0.f, 0.f, 0.f, 0.f};
    f32x4 acc01 = {0.f, 0.f, 0.f, 0.f}, acc11 = {0.f, 0.f, 0.f, 0.f};
#pragma unroll
    for (int k = 0; k < 128; k += 32) {
        bf16x8 bf0 = *(const bf16x8*)(b0 + k);
        bf16x8 bf1 = *(const bf16x8*)(b1 + k);
        bf16x8 af0 = *(const bf16x8*)&A[m][q * 8 + k];
        bf16x8 af1 = *(const bf16x8*)&A[16 + m][q * 8 + k];
        acc00 = __builtin_amdgcn_mfma_f32_16x16x32_bf16(af0, bf0, acc00, 0, 0, 0);
        acc10 = __builtin_amdgcn_mfma_f32_16x16x32_bf16(af1, bf0, acc10, 0, 0, 0);
        acc01 = __builtin_amdgcn_mfma_f32_16x16x32_bf16(af0, bf1, acc01, 0, 0, 0);
        acc11 = __builtin_amdgcn_mfma_f32_16x16x32_bf16(af1, bf1, acc11, 0, 0, 0);
    }
    int col0 = wv * 32 + m;
    int col1 = col0 + 16;
    float bc0 = bias[col0], bc1 = bias[col1];
#pragma unroll
    for (int r = 0; r < 4; r++) {
        int rr = row0 + q * 4 + r;
        int rr1 = rr + 16;
        float v00 = fmaxf(acc00[r] + bc0, 0.f);
        float v10 = fmaxf(acc10[r] + bc0, 0.f);
        float v01 = fmaxf(acc01[r] + bc1, 0.f);
        float v11 = fmaxf(acc11[r] + bc1, 0.f);
        float s0 = row_scale[rr], s1 = row_scale[rr1];
        v00 *= s0; v01 *= s0; v10 *= s1; v11 *= s1;
        C[(size_t)rr * 128 + col0]  = f2b(v00);
        C[(size_t)rr * 128 + col1]  = f2b(v01);
        C[(size_t)rr1 * 128 + col0] = f2b(v10);
        C[(size_t)rr1 * 128 + col1] = f2b(v11);
    }
}

// ---------- 9. fused conv2 + MLP, LDS 17408 B -> 8 blocks/CU ----------
// Regions: H1[32][136] at 0; region2 (A / H2 half-buffer, both [32][136]) at 4352.
// MLP2 K-loop split into two 128-halves (C0,D0,C1,D1); accumulator in registers,
// k-ascending order preserved -> bit-identical to the single-pass version.
__global__ __launch_bounds__(256, 8)
void k_conv2_mlp(const int* __restrict__ offsets, const int* __restrict__ esrc,
                 const uint4* __restrict__ feat, const float* __restrict__ in_norm,
                 const unsigned short* __restrict__ WT2, const float* __restrict__ b2,
                 const unsigned short* __restrict__ WTM1, const float* __restrict__ bm1,
                 const unsigned short* __restrict__ WTM2, const float* __restrict__ bm2,
                 float* __restrict__ out, int N) {
    __shared__ unsigned short smem[8704];                     // 17408 B
    unsigned short (*H1)[136] = (unsigned short(*)[136])(smem);
    unsigned short (*A)[136]  = (unsigned short(*)[136])(smem + 4352);
    unsigned short (*H2)[136] = (unsigned short(*)[136])(smem + 4352);  // alias of A

    int wv = threadIdx.x >> 6, lane = threadIdx.x & 63;
    int row0 = blockIdx.x * 32;
    int g = lane >> 4, c = lane & 15;

    // phase A: aggregate 32 nodes -> A
    for (int i = 0; i < 8; ++i) {
        int nl = wv * 8 + i;
        int node = row0 + nl;
        AGG_NODE_BODY(node)
        if (g == 0) {
            float inn = in_norm[node];
            uint4 o;
            o.x = pack2(a0 * inn, a1 * inn);
            o.y = pack2(a2 * inn, a3 * inn);
            o.z = pack2(a4 * inn, a5 * inn);
            o.w = pack2(a6 * inn, a7 * inn);
            *(uint4*)&A[nl][c * 8] = o;
        }
    }
    __syncthreads();

    int m = lane & 15, q = lane >> 4;

    // phase B: h2 = relu(A @ w2 + b2) -> H1 (H1 disjoint from A: no extra barrier)
    {
        const unsigned short* bb0 = WT2 + (size_t)(wv * 32 + m) * 128 + q * 8;
        const unsigned short* bb1 = bb0 + (size_t)16 * 128;
        f32x4 acc00 = {0.f, 0.f, 0.f, 0.f}, acc10 = {0.f, 0.f, 0.f, 0.f};
        f32x4 acc01 = {0.f, 0.f, 0.f, 0.f}, acc11 = {0.f, 0.f, 0.f, 0.f};
#pragma unroll
        for (int k = 0; k < 128; k += 32) {
            bf16x8 bf0 = *(const bf16x8*)(bb0 + k);
            bf16x8 bf1 = *(const bf16x8*)(bb1 + k);
            bf16x8 af0 = *(const bf16x8*)&A[m][q * 8 + k];
            bf16x8 af1 = *(const bf16x8*)&A[16 + m][q * 8 + k];
            acc00 = __builtin_amdgcn_mfma_f32_16x16x32_bf16(af0, bf0, acc00, 0, 0, 0);
            acc10 = __builtin_amdgcn_mfma_f32_16x16x32_bf16(af1, bf0, acc10, 0, 0, 0);
            acc01 = __builtin_amdgcn_mfma_f32_16x16x32_bf16(af0, bf1, acc01, 0, 0, 0);
            acc11 = __builtin_amdgcn_mfma_f32_16x16x32_bf16(af1, bf1, acc11, 0, 0, 0);
        }
        int col0 = wv * 32 + m;
        int col1 = col0 + 16;
        float bc0 = b2[col0], bc1 = b2[col1];
#pragma unroll
        for (int r = 0; r < 4; r++) {
            int rl = q * 4 + r;
            H1[rl][col0]      = f2b(fmaxf(acc00[r] + bc0, 0.f));
            H1[rl][col1]      = f2b(fmaxf(acc01[r] + bc1, 0.f));
            H1[rl + 16][col0] = f2b(fmaxf(acc10[r] + bc0, 0.f));
            H1[rl + 16][col1] = f2b(fmaxf(acc11[r] + bc1, 0.f));
        }
    }
    __syncthreads();   // H1 complete; all A reads done (H2 may now overwrite A)

    // phases C/D x2: mlp1 half -> H2, then mlp2 partial-K accumulate
    f32x4 macc0 = {0.f, 0.f, 0.f, 0.f}, macc1 = {0.f, 0.f, 0.f, 0.f};
    int colo = wv * 16 + m;
    const unsigned short* bp2 = WTM2 + (size_t)colo * 256 + q * 8;
#pragma unroll
    for (int half = 0; half < 2; ++half) {
        // C: mlp1 columns [half*128, half*128+128), full K=128 per column
#pragma unroll
        for (int cb = 0; cb < 2; cb++) {
            int colh = half * 128 + wv * 32 + cb * 16 + m;
            const unsigned short* bp = WTM1 + (size_t)colh * 128 + q * 8;
            f32x4 acc0 = {0.f, 0.f, 0.f, 0.f};
            f32x4 acc1 = {0.f, 0.f, 0.f, 0.f};
#pragma unroll
            for (int s = 0; s < 4; s++) {
                bf16x8 bfr = *(const bf16x8*)(bp + s * 32);
                bf16x8 ha0 = *(const bf16x8*)&H1[m][s * 32 + q * 8];
                bf16x8 ha1 = *(const bf16x8*)&H1[m + 16][s * 32 + q * 8];
                acc0 = __builtin_amdgcn_mfma_f32_16x16x32_bf16(ha0, bfr, acc0, 0, 0, 0);
                acc1 = __builtin_amdgcn_mfma_f32_16x16x32_bf16(ha1, bfr, acc1, 0, 0, 0);
            }
            float bc = bm1[colh];
            int cl = colh & 127;
#pragma unroll
            for (int r = 0; r < 4; r++) {
                H2[q * 4 + r][cl]      = f2b(fmaxf(acc0[r] + bc, 0.f));
                H2[q * 4 + r + 16][cl] = f2b(fmaxf(acc1[r] + bc, 0.f));
            }
        }
        __syncthreads();
        // D: mlp2 K-slice [half*128, half*128+128), k-ascending
#pragma unroll
        for (int s = 0; s < 4; s++) {
            bf16x8 bfr = *(const bf16x8*)(bp2 + half * 128 + s * 32);
            bf16x8 ha0 = *(const bf16x8*)&H2[m][s * 32 + q * 8];
            bf16x8 ha1 = *(const bf16x8*)&H2[m + 16][s * 32 + q * 8];
            macc0 = __builtin_amdgcn_mfma_f32_16x16x32_bf16(ha0, bfr, macc0, 0, 0, 0);
            macc1 = __builtin_amdgcn_mfma_f32_16x16x32_bf16(ha1, bfr, macc1, 0, 0, 0);
        }
        __syncthreads();   // H2 reads done before next half overwrites
    }

    float bc = bm2[colo];
#pragma unroll
    for (int r = 0; r < 4; r++) {
        out[(size_t)(row0 + q * 4 + r) * 64 + colo]      = macc0[r] + bc;
        out[(size_t)(row0 + q * 4 + r + 16) * 64 + colo] = macc1[r] + bc;
    }
}

extern "C" void kernel_launch(void* const* d_in, const int* in_sizes, int n_in,
                              void* d_out, int out_size, void* d_ws, size_t ws_size,
                              hipStream_t stream) {
    const float* x    = (const float*)d_in[0];
    const int*   src  = (const int*)d_in[1];
    const int*   dst  = (const int*)d_in[2];
    const float* w1   = (const float*)d_in[3];
    const float* b1   = (const float*)d_in[4];
    const float* w2   = (const float*)d_in[5];
    const float* b2   = (const float*)d_in[6];
    const float* wm1  = (const float*)d_in[7];
    const float* bm1  = (const float*)d_in[8];
    const float* wm2  = (const float*)d_in[9];
    const float* bm2  = (const float*)d_in[10];

    const int N = N_NODES;
    const int E = N_EDGES;

    char* p = (char*)d_ws;
    auto alloc = [&](size_t bytes) -> void* {
        void* r = (void*)p;
        p += (bytes + 255) & ~(size_t)255;
        return r;
    };
    int*   gcntA   = (int*)alloc(256 * 4);           // adjacent to gcntB: one memset
    int*   gcntB   = (int*)alloc(256 * 4);
    int*   gbaseA  = (int*)alloc(256 * 4);
    int*   gbaseB  = (int*)alloc(256 * 4);
    int*   gcurA   = (int*)alloc(256 * 4);
    int*   gcurB   = (int*)alloc(256 * 4);
    int*   offsets = (int*)alloc((size_t)(N + 1) * 4);
    float* out_norm = (float*)alloc((size_t)N * 4);
    float* in_norm  = (float*)alloc((size_t)N * 4);
    int*   esrc     = (int*)alloc((size_t)E * 4);
    unsigned int* bufA = (unsigned int*)alloc((size_t)N * 128 * 2);  // xs
    unsigned int* bufB = (unsigned int*)alloc((size_t)N * 128 * 2);  // pairs (build only)
    unsigned int* bufC = (unsigned int*)alloc((size_t)N * 128 * 2);  // keysB, then h1
    unsigned short* wt1  = (unsigned short*)alloc(128 * 128 * 2);
    unsigned short* wt2  = (unsigned short*)alloc(128 * 128 * 2);
    unsigned short* wtm1 = (unsigned short*)alloc(256 * 128 * 2);
    unsigned short* wtm2 = (unsigned short*)alloc(64 * 256 * 2);
    (void)ws_size; (void)n_in; (void)in_sizes; (void)out_size;

    unsigned* pairs = (unsigned*)bufB;   // packed (dloc<<17 | src), dead after k_csr_bucket
    int*      keysB = (int*)bufC;        // dead after k_count_scale (before bufC = h1)

    hipMemsetAsync(gcntA, 0, 2 * 256 * 4, stream);   // gcntA+gcntB contiguous

    const int TB = 256;
    // CSR build via two-level LDS counting sort (no per-edge global atomics)
    k_hist2<<<dim3(256), dim3(TB), 0, stream>>>(src, dst, gcntA, gcntB, E);
    k_scan_coarse<<<dim3(1), dim3(TB), 0, stream>>>(gcntA, gcntB, gbaseA, gbaseB,
                                                    gcurA, gcurB, offsets);
    k_scatter<<<dim3(256), dim3(TB), 0, stream>>>(src, dst, gcurA, gcurB, pairs, keysB, E);
    k_csr_bucket<<<dim3(NBUCK), dim3(1024), 0, stream>>>(pairs, gbaseA, offsets, in_norm, esrc);
    // canonicalize segment order (wave bitonic) -> bit-deterministic sums
    k_sortwave<<<dim3(N / 4), dim3(TB), 0, stream>>>(offsets, esrc, N);
    // out_norm from src counts + xs = bf16(x * out_norm), fused per bucket
    k_count_scale<<<dim3(NBUCK), dim3(1024), 0, stream>>>(
        keysB, gbaseB, (const float4*)x, out_norm, (uint2*)bufA);

    // all weight transposes (fp32 -> bf16) in one launch
    k_transpose4<<<dim3(320), dim3(TB), 0, stream>>>(w1, w2, wm1, wm2, wt1, wt2, wtm1, wtm2);

    // conv1: fused aggregate + gemm(w1) + relu + fold out_norm (bufA -> bufC)
    k_conv<<<dim3(N / 32), dim3(TB), 0, stream>>>(
        offsets, esrc, (const uint4*)bufA, in_norm, wt1, b1, out_norm,
        (unsigned short*)bufC, N);

    // conv2 + MLP: fused aggregate + gemm(w2) + mlp1 + mlp2 (bufC -> d_out)
    k_conv2_mlp<<<dim3(N / 32), dim3(TB), 0, stream>>>(
        offsets, esrc, (const uint4*)bufC, in_norm, wt2, b2, wtm1, bm1, wtm2, bm2,
        (float*)d_out, N);
}

// Round 4
// 581.114 us; speedup vs baseline: 1.3500x; 1.3500x over previous
//
#include <hip/hip_runtime.h>
#include <hip/hip_bf16.h>
#include <cstdint>

// ---------- bf16 helpers (raw ushort representation) ----------
__device__ __forceinline__ unsigned short f2b(float f) {
    union { float f; unsigned int i; } v; v.f = f;
    unsigned int i = v.i;
    unsigned int r = (i + 0x7FFFu + ((i >> 16) & 1u)) >> 16;   // RNE, finite inputs
    return (unsigned short)r;
}
__device__ __forceinline__ float b2f_lo(unsigned int p) {
    union { unsigned int i; float f; } v; v.i = p << 16; return v.f;
}
__device__ __forceinline__ float b2f_hi(unsigned int p) {
    union { unsigned int i; float f; } v; v.i = p & 0xFFFF0000u; return v.f;
}
__device__ __forceinline__ unsigned int pack2(float a, float b) {
    return (unsigned int)f2b(a) | ((unsigned int)f2b(b) << 16);
}

typedef __attribute__((__ext_vector_type__(8))) __bf16 bf16x8;
typedef __attribute__((__ext_vector_type__(4))) float  f32x4;

#define N_NODES 100000
#define N_EDGES 3200000
#define NBUCK   200        // coarse buckets
#define BSZ     500        // nodes per bucket (200*500 = 100000)

// ---------- 1. coarse histograms (dst and src) — LDS-privatized ----------
__global__ void k_hist2(const int* __restrict__ src, const int* __restrict__ dst,
                        int* __restrict__ gcntA, int* __restrict__ gcntB, int E) {
    __shared__ int hA[NBUCK], hB[NBUCK];
    int t = threadIdx.x;
    if (t < NBUCK) { hA[t] = 0; hB[t] = 0; }
    __syncthreads();
    for (int i = blockIdx.x * blockDim.x + t; i < E; i += gridDim.x * blockDim.x) {
        atomicAdd(&hA[dst[i] / BSZ], 1);
        atomicAdd(&hB[src[i] / BSZ], 1);
    }
    __syncthreads();
    if (t < NBUCK) {
        if (hA[t]) atomicAdd(&gcntA[t], hA[t]);
        if (hB[t]) atomicAdd(&gcntB[t], hB[t]);
    }
}

// ---------- 2. scan coarse counts -> bucket bases + cursors ----------
__global__ void k_scan_coarse(const int* __restrict__ gcntA, const int* __restrict__ gcntB,
                              int* __restrict__ gbaseA, int* __restrict__ gbaseB,
                              int* __restrict__ gcurA, int* __restrict__ gcurB,
                              int* __restrict__ offsets) {
    __shared__ int pA[256], pB[256];
    int t = threadIdx.x;
    int vA = (t < NBUCK) ? gcntA[t] : 0;
    int vB = (t < NBUCK) ? gcntB[t] : 0;
    pA[t] = vA; pB[t] = vB;
    __syncthreads();
    for (int d = 1; d < 256; d <<= 1) {
        int a = (t >= d) ? pA[t - d] : 0;
        int b = (t >= d) ? pB[t - d] : 0;
        __syncthreads();
        pA[t] += a; pB[t] += b;
        __syncthreads();
    }
    if (t < NBUCK) {
        gbaseA[t] = pA[t] - vA; gcurA[t] = pA[t] - vA;
        gbaseB[t] = pB[t] - vB; gcurB[t] = pB[t] - vB;
    }
    if (t == 255) {
        gbaseA[NBUCK] = pA[255];
        gbaseB[NBUCK] = pB[255];
        offsets[N_NODES] = pA[255];   // == E
    }
}

// ---------- 3. scatter: packed u32 (dloc<<17|src) by dst bucket; keys by src bucket ----------
__global__ void k_scatter(const int* __restrict__ src, const int* __restrict__ dst,
                          int* __restrict__ gcurA, int* __restrict__ gcurB,
                          unsigned* __restrict__ pairs, int* __restrict__ keysB, int E) {
    __shared__ int hA[NBUCK], hB[NBUCK], baA[NBUCK], baB[NBUCK], lcA[NBUCK], lcB[NBUCK];
    int t = threadIdx.x;
    const int CHUNK = 12500;                       // E / 256 blocks
    int lo = blockIdx.x * CHUNK, hi = min(lo + CHUNK, E);
    if (t < NBUCK) { hA[t] = 0; hB[t] = 0; }
    __syncthreads();
    for (int i = lo + t; i < hi; i += 256) {
        atomicAdd(&hA[dst[i] / BSZ], 1);
        atomicAdd(&hB[src[i] / BSZ], 1);
    }
    __syncthreads();
    if (t < NBUCK) {
        baA[t] = hA[t] ? atomicAdd(&gcurA[t], hA[t]) : 0;
        lcA[t] = 0;
        baB[t] = hB[t] ? atomicAdd(&gcurB[t], hB[t]) : 0;
        lcB[t] = 0;
    }
    __syncthreads();
    for (int i = lo + t; i < hi; i += 256) {
        int s = src[i], d = dst[i];
        int bA = d / BSZ;
        int l  = atomicAdd(&lcA[bA], 1);
        pairs[baA[bA] + l] = ((unsigned)(d - bA * BSZ) << 17) | (unsigned)s;
        int bB = s / BSZ;
        int l2 = atomicAdd(&lcB[bB], 1);
        keysB[baB[bB] + l2] = s;
    }
}

// ---------- 4. per-bucket CSR finalize: offsets, in_norm, esrc ----------
__global__ void k_csr_bucket(const unsigned* __restrict__ pairs, const int* __restrict__ gbaseA,
                             int* __restrict__ offsets, float* __restrict__ in_norm,
                             int* __restrict__ esrc) {
    __shared__ int hist[512], scan[512], curs[512];
    int b = blockIdx.x, t = threadIdx.x;
    int node0 = b * BSZ;
    int bstart = gbaseA[b], bend = gbaseA[b + 1];
    if (t < 512) hist[t] = 0;
    __syncthreads();
    for (int i = bstart + t; i < bend; i += 1024)
        atomicAdd(&hist[pairs[i] >> 17], 1);
    __syncthreads();
    if (t < 512) scan[t] = hist[t];
    __syncthreads();
    for (int d = 1; d < 512; d <<= 1) {
        int v = (t < 512 && t >= d) ? scan[t - d] : 0;
        __syncthreads();
        if (t < 512) scan[t] += v;
        __syncthreads();
    }
    if (t < BSZ) {
        int excl = scan[t] - hist[t];
        offsets[node0 + t] = bstart + excl;
        in_norm[node0 + t] = rsqrtf((float)max(hist[t], 1));
        curs[t] = excl;
    }
    __syncthreads();
    for (int i = bstart + t; i < bend; i += 1024) {
        unsigned p = pairs[i];
        int d = (int)(p >> 17);
        int l = atomicAdd(&curs[d], 1);
        esrc[bstart + l] = (int)(p & 0x1FFFFu);
    }
}

// ---------- 4b. canonicalize: wave-parallel bitonic sort of each segment ----------
__global__ void k_sortwave(const int* __restrict__ offsets, int* __restrict__ esrc, int N) {
    int node = blockIdx.x * 4 + (threadIdx.x >> 6);
    if (node >= N) return;
    int lane = threadIdx.x & 63;
    int lo = offsets[node], hi = offsets[node + 1];
    int len = hi - lo;
    if (len <= 1) return;
    const int INF = 0x7FFFFFFF;
    int v0 = (lane < len) ? esrc[lo + lane] : INF;
    int v1 = (64 + lane < len) ? esrc[lo + 64 + lane] : INF;
#pragma unroll
    for (int k = 2; k <= 128; k <<= 1) {
#pragma unroll
        for (int d = 64; d > 0; d >>= 1) {
            if (d >= k) continue;
            if (d == 64) {
                int a = min(v0, v1), b = max(v0, v1);
                v0 = a; v1 = b;
            } else {
                int w0 = __shfl_xor(v0, d, 64);
                int w1 = __shfl_xor(v1, d, 64);
                bool up0 = ((lane & k) == 0);
                bool up1 = (((64 + lane) & k) == 0);
                bool lower = ((lane & d) == 0);
                v0 = (lower == up0) ? min(v0, w0) : max(v0, w0);
                v1 = (lower == up1) ? min(v1, w1) : max(v1, w1);
            }
        }
    }
    if (lane < len) esrc[lo + lane] = v0;
    if (64 + lane < len) esrc[lo + 64 + lane] = v1;
}

// ---------- 5. fused: per-bucket src count -> out_norm + scale bucket's features ----------
__global__ void k_count_scale(const int* __restrict__ keys, const int* __restrict__ gbaseB,
                              const float4* __restrict__ x4, float* __restrict__ out_norm,
                              uint2* __restrict__ xs) {
    __shared__ int hist[512];
    __shared__ float onl[BSZ];
    int b = blockIdx.x, t = threadIdx.x;
    int node0 = b * BSZ;
    int bstart = gbaseB[b], bend = gbaseB[b + 1];
    if (t < 512) hist[t] = 0;
    __syncthreads();
    for (int i = bstart + t; i < bend; i += 1024)
        atomicAdd(&hist[keys[i] - node0], 1);
    __syncthreads();
    if (t < BSZ) {
        float on = rsqrtf((float)max(hist[t], 1));
        onl[t] = on;
        out_norm[node0 + t] = on;
    }
    __syncthreads();
    // scale this bucket's 500 x 128 features: xs = bf16(x * out_norm)
    size_t base4 = (size_t)node0 * 32;
    for (int i = t; i < BSZ * 32; i += 1024) {
        float on = onl[i >> 5];
        float4 v = x4[base4 + i];
        uint2 o;
        o.x = pack2(v.x * on, v.y * on);
        o.y = pack2(v.z * on, v.w * on);
        xs[base4 + i] = o;
    }
}

// ---------- 7. merged weight transpose + bf16 cast (all four weights) ----------
__global__ void k_transpose4(const float* __restrict__ w1, const float* __restrict__ w2,
                             const float* __restrict__ wm1, const float* __restrict__ wm2,
                             unsigned short* __restrict__ t1, unsigned short* __restrict__ t2,
                             unsigned short* __restrict__ tm1, unsigned short* __restrict__ tm2) {
    int i = blockIdx.x * blockDim.x + threadIdx.x;
    const float* w; unsigned short* t; int N, idx;
    if (i < 16384)       { w = w1;  t = t1;  N = 128; idx = i; }
    else if (i < 32768)  { w = w2;  t = t2;  N = 128; idx = i - 16384; }
    else if (i < 65536)  { w = wm1; t = tm1; N = 256; idx = i - 32768; }
    else if (i < 81920)  { w = wm2; t = tm2; N = 64;  idx = i - 65536; }
    else return;
    int K = (i < 65536) ? 128 : 256;
    int k = idx / N, n = idx - k * N;
    t[(size_t)n * K + k] = f2b(w[idx]);
}

// ---------- aggregate inner body: verified 4-deep unroll (VGPR-safe at 64-cap) ----------
// Per-lane summation order strictly ascending k -> bit-identical results.
// NOTE (round 3 lesson): 8-deep unroll under __launch_bounds__(256,8) (64 VGPR cap)
// spills the gather payloads to scratch: WRITE_SIZE 25->316 MB, k_conv 103->296 µs.
// Keep this at 4-deep unless launch bounds are relaxed.
#define AGG_ADD(p)                                                              \
        a0 += b2f_lo(p.x); a1 += b2f_hi(p.x);                                   \
        a2 += b2f_lo(p.y); a3 += b2f_hi(p.y);                                   \
        a4 += b2f_lo(p.z); a5 += b2f_hi(p.z);                                   \
        a6 += b2f_lo(p.w); a7 += b2f_hi(p.w);

#define AGG_NODE_BODY(node)                                                     \
    int lo = offsets[node], hi = offsets[node + 1];                             \
    float a0 = 0.f, a1 = 0.f, a2 = 0.f, a3 = 0.f,                               \
          a4 = 0.f, a5 = 0.f, a6 = 0.f, a7 = 0.f;                               \
    int k = lo + g;                                                             \
    for (; k + 12 < hi; k += 16) {                                              \
        int s0 = esrc[k];                                                       \
        int s1 = esrc[k + 4];                                                   \
        int s2 = esrc[k + 8];                                                   \
        int s3 = esrc[k + 12];                                                  \
        uint4 p0 = feat[(size_t)s0 * 16 + c];                                   \
        uint4 p1 = feat[(size_t)s1 * 16 + c];                                   \
        uint4 p2 = feat[(size_t)s2 * 16 + c];                                   \
        uint4 p3 = feat[(size_t)s3 * 16 + c];                                   \
        AGG_ADD(p0) AGG_ADD(p1) AGG_ADD(p2) AGG_ADD(p3)                         \
    }                                                                           \
    for (; k < hi; k += 4) {                                                    \
        int s = esrc[k];                                                        \
        uint4 p = feat[(size_t)s * 16 + c];                                     \
        AGG_ADD(p)                                                              \
    }                                                                           \
    a0 += __shfl_xor(a0, 16, 64); a0 += __shfl_xor(a0, 32, 64);                 \
    a1 += __shfl_xor(a1, 16, 64); a1 += __shfl_xor(a1, 32, 64);                 \
    a2 += __shfl_xor(a2, 16, 64); a2 += __shfl_xor(a2, 32, 64);                 \
    a3 += __shfl_xor(a3, 16, 64); a3 += __shfl_xor(a3, 32, 64);                 \
    a4 += __shfl_xor(a4, 16, 64); a4 += __shfl_xor(a4, 32, 64);                 \
    a5 += __shfl_xor(a5, 16, 64); a5 += __shfl_xor(a5, 32, 64);                 \
    a6 += __shfl_xor(a6, 16, 64); a6 += __shfl_xor(a6, 32, 64);                 \
    a7 += __shfl_xor(a7, 16, 64); a7 += __shfl_xor(a7, 32, 64);

// ---------- 8. fused conv1: aggregate(32 nodes) -> LDS -> MFMA GEMM -> relu*scale ----------
// LDS 8704 B, 4 waves/block -> 8 blocks/CU (wave-capped, 100% occupancy).
__global__ __launch_bounds__(256, 8)
void k_conv(const int* __restrict__ offsets, const int* __restrict__ esrc,
            const uint4* __restrict__ feat, const float* __restrict__ in_norm,
            const unsigned short* __restrict__ WT, const float* __restrict__ bias,
            const float* __restrict__ row_scale, unsigned short* __restrict__ C,
            int N) {
    __shared__ unsigned short A[32][136];       // 272B row stride, 16B-aligned rows
    int wv = threadIdx.x >> 6, lane = threadIdx.x & 63;
    int row0 = blockIdx.x * 32;
    int g = lane >> 4, c = lane & 15;

    // phase A: aggregate
    for (int i = 0; i < 8; ++i) {
        int nl = wv * 8 + i;
        int node = row0 + nl;
        AGG_NODE_BODY(node)
        if (g == 0) {
            float inn = in_norm[node];
            uint4 o;
            o.x = pack2(a0 * inn, a1 * inn);
            o.y = pack2(a2 * inn, a3 * inn);
            o.z = pack2(a4 * inn, a5 * inn);
            o.w = pack2(a6 * inn, a7 * inn);
            *(uint4*)&A[nl][c * 8] = o;
        }
    }
    __syncthreads();

    // phase B: GEMM 32x128 tile, wave covers cols wv*32 .. wv*32+31
    int m = lane & 15, q = lane >> 4;
    const unsigned short* b0 = WT + (size_t)(wv * 32 + m) * 128 + q * 8;
    const unsigned short* b1 = b0 + (size_t)16 * 128;
    f32x4 acc00 = {0.f, 0.f, 0.f, 0.f}, acc10 = {0.f, 0.f, 0.f, 0.f};
    f32x4 acc01 = {0.f, 0.f, 0.f, 0.f}, acc11 = {0.f, 0.f, 0.f, 0.f};
#pragma unroll
    for (int k = 0; k < 128; k += 32) {
        bf16x8 bf0 = *(const bf16x8*)(b0 + k);
        bf16x8 bf1 = *(const bf16x8*)(b1 + k);
        bf16x8 af0 = *(const bf16x8*)&A[m][q * 8 + k];
        bf16x8 af1 = *(const bf16x8*)&A[16 + m][q * 8 + k];
        acc00 = __builtin_amdgcn_mfma_f32_16x16x32_bf16(af0, bf0, acc00, 0, 0, 0);
        acc10 = __builtin_amdgcn_mfma_f32_16x16x32_bf16(af1, bf0, acc10, 0, 0, 0);
        acc01 = __builtin_amdgcn_mfma_f32_16x16x32_bf16(af0, bf1, acc01, 0, 0, 0);
        acc11 = __builtin_amdgcn_mfma_f32_16x16x32_bf16(af1, bf1, acc11, 0, 0, 0);
    }
    int col0 = wv * 32 + m;
    int col1 = col0 + 16;
    float bc0 = bias[col0], bc1 = bias[col1];
#pragma unroll
    for (int r = 0; r < 4; r++) {
        int rr = row0 + q * 4 + r;
        int rr1 = rr + 16;
        float v00 = fmaxf(acc00[r] + bc0, 0.f);
        float v10 = fmaxf(acc10[r] + bc0, 0.f);
        float v01 = fmaxf(acc01[r] + bc1, 0.f);
        float v11 = fmaxf(acc11[r] + bc1, 0.f);
        float s0 = row_scale[rr], s1 = row_scale[rr1];
        v00 *= s0; v01 *= s0; v10 *= s1; v11 *= s1;
        C[(size_t)rr * 128 + col0]  = f2b(v00);
        C[(size_t)rr * 128 + col1]  = f2b(v01);
        C[(size_t)rr1 * 128 + col0] = f2b(v10);
        C[(size_t)rr1 * 128 + col1] = f2b(v11);
    }
}

// ---------- 9. fused conv2 + MLP, LDS 17408 B -> 8 blocks/CU ----------
// Regions: H1[32][136] at 0; region2 (A / H2 half-buffer, both [32][136]) at 4352.
// MLP2 K-loop split into two 128-halves (C0,D0,C1,D1); accumulator in registers,
// k-ascending order preserved -> bit-identical to the single-pass version.
__global__ __launch_bounds__(256, 8)
void k_conv2_mlp(const int* __restrict__ offsets, const int* __restrict__ esrc,
                 const uint4* __restrict__ feat, const float* __restrict__ in_norm,
                 const unsigned short* __restrict__ WT2, const float* __restrict__ b2,
                 const unsigned short* __restrict__ WTM1, const float* __restrict__ bm1,
                 const unsigned short* __restrict__ WTM2, const float* __restrict__ bm2,
                 float* __restrict__ out, int N) {
    __shared__ unsigned short smem[8704];                     // 17408 B
    unsigned short (*H1)[136] = (unsigned short(*)[136])(smem);
    unsigned short (*A)[136]  = (unsigned short(*)[136])(smem + 4352);
    unsigned short (*H2)[136] = (unsigned short(*)[136])(smem + 4352);  // alias of A

    int wv = threadIdx.x >> 6, lane = threadIdx.x & 63;
    int row0 = blockIdx.x * 32;
    int g = lane >> 4, c = lane & 15;

    // phase A: aggregate 32 nodes -> A
    for (int i = 0; i < 8; ++i) {
        int nl = wv * 8 + i;
        int node = row0 + nl;
        AGG_NODE_BODY(node)
        if (g == 0) {
            float inn = in_norm[node];
            uint4 o;
            o.x = pack2(a0 * inn, a1 * inn);
            o.y = pack2(a2 * inn, a3 * inn);
            o.z = pack2(a4 * inn, a5 * inn);
            o.w = pack2(a6 * inn, a7 * inn);
            *(uint4*)&A[nl][c * 8] = o;
        }
    }
    __syncthreads();

    int m = lane & 15, q = lane >> 4;

    // phase B: h2 = relu(A @ w2 + b2) -> H1 (H1 disjoint from A: no extra barrier)
    {
        const unsigned short* bb0 = WT2 + (size_t)(wv * 32 + m) * 128 + q * 8;
        const unsigned short* bb1 = bb0 + (size_t)16 * 128;
        f32x4 acc00 = {0.f, 0.f, 0.f, 0.f}, acc10 = {0.f, 0.f, 0.f, 0.f};
        f32x4 acc01 = {0.f, 0.f, 0.f, 0.f}, acc11 = {0.f, 0.f, 0.f, 0.f};
#pragma unroll
        for (int k = 0; k < 128; k += 32) {
            bf16x8 bf0 = *(const bf16x8*)(bb0 + k);
            bf16x8 bf1 = *(const bf16x8*)(bb1 + k);
            bf16x8 af0 = *(const bf16x8*)&A[m][q * 8 + k];
            bf16x8 af1 = *(const bf16x8*)&A[16 + m][q * 8 + k];
            acc00 = __builtin_amdgcn_mfma_f32_16x16x32_bf16(af0, bf0, acc00, 0, 0, 0);
            acc10 = __builtin_amdgcn_mfma_f32_16x16x32_bf16(af1, bf0, acc10, 0, 0, 0);
            acc01 = __builtin_amdgcn_mfma_f32_16x16x32_bf16(af0, bf1, acc01, 0, 0, 0);
            acc11 = __builtin_amdgcn_mfma_f32_16x16x32_bf16(af1, bf1, acc11, 0, 0, 0);
        }
        int col0 = wv * 32 + m;
        int col1 = col0 + 16;
        float bc0 = b2[col0], bc1 = b2[col1];
#pragma unroll
        for (int r = 0; r < 4; r++) {
            int rl = q * 4 + r;
            H1[rl][col0]      = f2b(fmaxf(acc00[r] + bc0, 0.f));
            H1[rl][col1]      = f2b(fmaxf(acc01[r] + bc1, 0.f));
            H1[rl + 16][col0] = f2b(fmaxf(acc10[r] + bc0, 0.f));
            H1[rl + 16][col1] = f2b(fmaxf(acc11[r] + bc1, 0.f));
        }
    }
    __syncthreads();   // H1 complete; all A reads done (H2 may now overwrite A)

    // phases C/D x2: mlp1 half -> H2, then mlp2 partial-K accumulate
    f32x4 macc0 = {0.f, 0.f, 0.f, 0.f}, macc1 = {0.f, 0.f, 0.f, 0.f};
    int colo = wv * 16 + m;
    const unsigned short* bp2 = WTM2 + (size_t)colo * 256 + q * 8;
#pragma unroll
    for (int half = 0; half < 2; ++half) {
        // C: mlp1 columns [half*128, half*128+128), full K=128 per column
#pragma unroll
        for (int cb = 0; cb < 2; cb++) {
            int colh = half * 128 + wv * 32 + cb * 16 + m;
            const unsigned short* bp = WTM1 + (size_t)colh * 128 + q * 8;
            f32x4 acc0 = {0.f, 0.f, 0.f, 0.f};
            f32x4 acc1 = {0.f, 0.f, 0.f, 0.f};
#pragma unroll
            for (int s = 0; s < 4; s++) {
                bf16x8 bfr = *(const bf16x8*)(bp + s * 32);
                bf16x8 ha0 = *(const bf16x8*)&H1[m][s * 32 + q * 8];
                bf16x8 ha1 = *(const bf16x8*)&H1[m + 16][s * 32 + q * 8];
                acc0 = __builtin_amdgcn_mfma_f32_16x16x32_bf16(ha0, bfr, acc0, 0, 0, 0);
                acc1 = __builtin_amdgcn_mfma_f32_16x16x32_bf16(ha1, bfr, acc1, 0, 0, 0);
            }
            float bc = bm1[colh];
            int cl = colh & 127;
#pragma unroll
            for (int r = 0; r < 4; r++) {
                H2[q * 4 + r][cl]      = f2b(fmaxf(acc0[r] + bc, 0.f));
                H2[q * 4 + r + 16][cl] = f2b(fmaxf(acc1[r] + bc, 0.f));
            }
        }
        __syncthreads();
        // D: mlp2 K-slice [half*128, half*128+128), k-ascending
#pragma unroll
        for (int s = 0; s < 4; s++) {
            bf16x8 bfr = *(const bf16x8*)(bp2 + half * 128 + s * 32);
            bf16x8 ha0 = *(const bf16x8*)&H2[m][s * 32 + q * 8];
            bf16x8 ha1 = *(const bf16x8*)&H2[m + 16][s * 32 + q * 8];
            macc0 = __builtin_amdgcn_mfma_f32_16x16x32_bf16(ha0, bfr, macc0, 0, 0, 0);
            macc1 = __builtin_amdgcn_mfma_f32_16x16x32_bf16(ha1, bfr, macc1, 0, 0, 0);
        }
        __syncthreads();   // H2 reads done before next half overwrites
    }

    float bc = bm2[colo];
#pragma unroll
    for (int r = 0; r < 4; r++) {
        out[(size_t)(row0 + q * 4 + r) * 64 + colo]      = macc0[r] + bc;
        out[(size_t)(row0 + q * 4 + r + 16) * 64 + colo] = macc1[r] + bc;
    }
}

extern "C" void kernel_launch(void* const* d_in, const int* in_sizes, int n_in,
                              void* d_out, int out_size, void* d_ws, size_t ws_size,
                              hipStream_t stream) {
    const float* x    = (const float*)d_in[0];
    const int*   src  = (const int*)d_in[1];
    const int*   dst  = (const int*)d_in[2];
    const float* w1   = (const float*)d_in[3];
    const float* b1   = (const float*)d_in[4];
    const float* w2   = (const float*)d_in[5];
    const float* b2   = (const float*)d_in[6];
    const float* wm1  = (const float*)d_in[7];
    const float* bm1  = (const float*)d_in[8];
    const float* wm2  = (const float*)d_in[9];
    const float* bm2  = (const float*)d_in[10];

    const int N = N_NODES;
    const int E = N_EDGES;

    char* p = (char*)d_ws;
    auto alloc = [&](size_t bytes) -> void* {
        void* r = (void*)p;
        p += (bytes + 255) & ~(size_t)255;
        return r;
    };
    int*   gcntA   = (int*)alloc(256 * 4);           // adjacent to gcntB: one memset
    int*   gcntB   = (int*)alloc(256 * 4);
    int*   gbaseA  = (int*)alloc(256 * 4);
    int*   gbaseB  = (int*)alloc(256 * 4);
    int*   gcurA   = (int*)alloc(256 * 4);
    int*   gcurB   = (int*)alloc(256 * 4);
    int*   offsets = (int*)alloc((size_t)(N + 1) * 4);
    float* out_norm = (float*)alloc((size_t)N * 4);
    float* in_norm  = (float*)alloc((size_t)N * 4);
    int*   esrc     = (int*)alloc((size_t)E * 4);
    unsigned int* bufA = (unsigned int*)alloc((size_t)N * 128 * 2);  // xs
    unsigned int* bufB = (unsigned int*)alloc((size_t)N * 128 * 2);  // pairs (build only)
    unsigned int* bufC = (unsigned int*)alloc((size_t)N * 128 * 2);  // keysB, then h1
    unsigned short* wt1  = (unsigned short*)alloc(128 * 128 * 2);
    unsigned short* wt2  = (unsigned short*)alloc(128 * 128 * 2);
    unsigned short* wtm1 = (unsigned short*)alloc(256 * 128 * 2);
    unsigned short* wtm2 = (unsigned short*)alloc(64 * 256 * 2);
    (void)ws_size; (void)n_in; (void)in_sizes; (void)out_size;

    unsigned* pairs = (unsigned*)bufB;   // packed (dloc<<17 | src), dead after k_csr_bucket
    int*      keysB = (int*)bufC;        // dead after k_count_scale (before bufC = h1)

    hipMemsetAsync(gcntA, 0, 2 * 256 * 4, stream);   // gcntA+gcntB contiguous

    const int TB = 256;
    // CSR build via two-level LDS counting sort (no per-edge global atomics)
    k_hist2<<<dim3(256), dim3(TB), 0, stream>>>(src, dst, gcntA, gcntB, E);
    k_scan_coarse<<<dim3(1), dim3(TB), 0, stream>>>(gcntA, gcntB, gbaseA, gbaseB,
                                                    gcurA, gcurB, offsets);
    k_scatter<<<dim3(256), dim3(TB), 0, stream>>>(src, dst, gcurA, gcurB, pairs, keysB, E);
    k_csr_bucket<<<dim3(NBUCK), dim3(1024), 0, stream>>>(pairs, gbaseA, offsets, in_norm, esrc);
    // canonicalize segment order (wave bitonic) -> bit-deterministic sums
    k_sortwave<<<dim3(N / 4), dim3(TB), 0, stream>>>(offsets, esrc, N);
    // out_norm from src counts + xs = bf16(x * out_norm), fused per bucket
    k_count_scale<<<dim3(NBUCK), dim3(1024), 0, stream>>>(
        keysB, gbaseB, (const float4*)x, out_norm, (uint2*)bufA);

    // all weight transposes (fp32 -> bf16) in one launch
    k_transpose4<<<dim3(320), dim3(TB), 0, stream>>>(w1, w2, wm1, wm2, wt1, wt2, wtm1, wtm2);

    // conv1: fused aggregate + gemm(w1) + relu + fold out_norm (bufA -> bufC)
    k_conv<<<dim3(N / 32), dim3(TB), 0, stream>>>(
        offsets, esrc, (const uint4*)bufA, in_norm, wt1, b1, out_norm,
        (unsigned short*)bufC, N);

    // conv2 + MLP: fused aggregate + gemm(w2) + mlp1 + mlp2 (bufC -> d_out)
    k_conv2_mlp<<<dim3(N / 32), dim3(TB), 0, stream>>>(
        offsets, esrc, (const uint4*)bufC, in_norm, wt2, b2, wtm1, bm1, wtm2, bm2,
        (float*)d_out, N);
}

// Round 5
// 552.630 us; speedup vs baseline: 1.4195x; 1.0515x over previous
//
#include <hip/hip_runtime.h>
#include <hip/hip_bf16.h>
#include <cstdint>

// ---------- bf16 helpers (raw ushort representation) ----------
__device__ __forceinline__ unsigned short f2b(float f) {
    union { float f; unsigned int i; } v; v.f = f;
    unsigned int i = v.i;
    unsigned int r = (i + 0x7FFFu + ((i >> 16) & 1u)) >> 16;   // RNE, finite inputs
    return (unsigned short)r;
}
__device__ __forceinline__ float b2f_lo(unsigned int p) {
    union { unsigned int i; float f; } v; v.i = p << 16; return v.f;
}
__device__ __forceinline__ float b2f_hi(unsigned int p) {
    union { unsigned int i; float f; } v; v.i = p & 0xFFFF0000u; return v.f;
}
__device__ __forceinline__ unsigned int pack2(float a, float b) {
    return (unsigned int)f2b(a) | ((unsigned int)f2b(b) << 16);
}

typedef __attribute__((__ext_vector_type__(8))) __bf16 bf16x8;
typedef __attribute__((__ext_vector_type__(4))) float  f32x4;

#define N_NODES 100000
#define N_EDGES 3200000
#define NBUCK   400        // coarse buckets (400 blocks -> full 256-CU coverage)
#define BSZ     250        // nodes per bucket (400*250 = 100000)

// ---------- 1. coarse histograms (dst and src) — LDS-privatized ----------
__global__ void k_hist2(const int* __restrict__ src, const int* __restrict__ dst,
                        int* __restrict__ gcntA, int* __restrict__ gcntB, int E) {
    __shared__ int hA[NBUCK], hB[NBUCK];
    int t = threadIdx.x;
    for (int j = t; j < NBUCK; j += 256) { hA[j] = 0; hB[j] = 0; }
    __syncthreads();
    for (int i = blockIdx.x * blockDim.x + t; i < E; i += gridDim.x * blockDim.x) {
        atomicAdd(&hA[dst[i] / BSZ], 1);
        atomicAdd(&hB[src[i] / BSZ], 1);
    }
    __syncthreads();
    for (int j = t; j < NBUCK; j += 256) {
        if (hA[j]) atomicAdd(&gcntA[j], hA[j]);
        if (hB[j]) atomicAdd(&gcntB[j], hB[j]);
    }
}

// ---------- 2. scan coarse counts -> bucket bases + cursors (512 threads) ----------
__global__ void k_scan_coarse(const int* __restrict__ gcntA, const int* __restrict__ gcntB,
                              int* __restrict__ gbaseA, int* __restrict__ gbaseB,
                              int* __restrict__ gcurA, int* __restrict__ gcurB,
                              int* __restrict__ offsets) {
    __shared__ int pA[512], pB[512];
    int t = threadIdx.x;
    int vA = (t < NBUCK) ? gcntA[t] : 0;
    int vB = (t < NBUCK) ? gcntB[t] : 0;
    pA[t] = vA; pB[t] = vB;
    __syncthreads();
    for (int d = 1; d < 512; d <<= 1) {
        int a = (t >= d) ? pA[t - d] : 0;
        int b = (t >= d) ? pB[t - d] : 0;
        __syncthreads();
        pA[t] += a; pB[t] += b;
        __syncthreads();
    }
    if (t < NBUCK) {
        gbaseA[t] = pA[t] - vA; gcurA[t] = pA[t] - vA;
        gbaseB[t] = pB[t] - vB; gcurB[t] = pB[t] - vB;
    }
    if (t == 511) {
        gbaseA[NBUCK] = pA[511];
        gbaseB[NBUCK] = pB[511];
        offsets[N_NODES] = pA[511];   // == E
    }
}

// ---------- 3. scatter: packed u32 (dloc<<17|src) by dst bucket; u16 keys by src bucket ----------
__global__ void k_scatter(const int* __restrict__ src, const int* __restrict__ dst,
                          int* __restrict__ gcurA, int* __restrict__ gcurB,
                          unsigned* __restrict__ pairs, unsigned short* __restrict__ keysB,
                          int E) {
    __shared__ int hA[NBUCK], hB[NBUCK], baA[NBUCK], baB[NBUCK], lcA[NBUCK], lcB[NBUCK];
    int t = threadIdx.x;
    const int CHUNK = 12500;                       // E / 256 blocks
    int lo = blockIdx.x * CHUNK, hi = min(lo + CHUNK, E);
    for (int j = t; j < NBUCK; j += 256) { hA[j] = 0; hB[j] = 0; }
    __syncthreads();
    for (int i = lo + t; i < hi; i += 256) {
        atomicAdd(&hA[dst[i] / BSZ], 1);
        atomicAdd(&hB[src[i] / BSZ], 1);
    }
    __syncthreads();
    for (int j = t; j < NBUCK; j += 256) {
        baA[j] = hA[j] ? atomicAdd(&gcurA[j], hA[j]) : 0;
        lcA[j] = 0;
        baB[j] = hB[j] ? atomicAdd(&gcurB[j], hB[j]) : 0;
        lcB[j] = 0;
    }
    __syncthreads();
    for (int i = lo + t; i < hi; i += 256) {
        int s = src[i], d = dst[i];
        int bA = d / BSZ;
        int l  = atomicAdd(&lcA[bA], 1);
        pairs[baA[bA] + l] = ((unsigned)(d - bA * BSZ) << 17) | (unsigned)s;
        int bB = s / BSZ;
        int l2 = atomicAdd(&lcB[bB], 1);
        keysB[baB[bB] + l2] = (unsigned short)(s - bB * BSZ);
    }
}

// ---------- 4. per-bucket CSR finalize: offsets, in_norm, esrc (400 x 512) ----------
__global__ void k_csr_bucket(const unsigned* __restrict__ pairs, const int* __restrict__ gbaseA,
                             int* __restrict__ offsets, float* __restrict__ in_norm,
                             int* __restrict__ esrc) {
    __shared__ int hist[256], scan[256], curs[256];
    int b = blockIdx.x, t = threadIdx.x;
    int node0 = b * BSZ;
    int bstart = gbaseA[b], bend = gbaseA[b + 1];
    if (t < 256) hist[t] = 0;
    __syncthreads();
    for (int i = bstart + t; i < bend; i += 512)
        atomicAdd(&hist[pairs[i] >> 17], 1);
    __syncthreads();
    if (t < 256) scan[t] = hist[t];
    __syncthreads();
    for (int d = 1; d < 256; d <<= 1) {
        int v = (t < 256 && t >= d) ? scan[t - d] : 0;
        __syncthreads();
        if (t < 256) scan[t] += v;
        __syncthreads();
    }
    if (t < BSZ) {
        int excl = scan[t] - hist[t];
        offsets[node0 + t] = bstart + excl;
        in_norm[node0 + t] = rsqrtf((float)max(hist[t], 1));
        curs[t] = excl;
    }
    __syncthreads();
    for (int i = bstart + t; i < bend; i += 512) {
        unsigned p = pairs[i];
        int d = (int)(p >> 17);
        int l = atomicAdd(&curs[d], 1);
        esrc[bstart + l] = (int)(p & 0x1FFFFu);
    }
}

// ---------- 4b. canonicalize: wave-parallel bitonic sort of each segment ----------
// fast path: deg ~ Binomial(E,1/N) => len<=64 for ~99.94% of nodes (single-reg sort)
__global__ void k_sortwave(const int* __restrict__ offsets, int* __restrict__ esrc, int N) {
    int node = blockIdx.x * 4 + (threadIdx.x >> 6);
    if (node >= N) return;
    int lane = threadIdx.x & 63;
    int lo = offsets[node], hi = offsets[node + 1];
    int len = hi - lo;
    if (len <= 1) return;
    const int INF = 0x7FFFFFFF;
    if (len <= 64) {
        int v0 = (lane < len) ? esrc[lo + lane] : INF;
#pragma unroll
        for (int k = 2; k <= 64; k <<= 1) {
#pragma unroll
            for (int d = 32; d > 0; d >>= 1) {
                if (d >= k) continue;
                int w0 = __shfl_xor(v0, d, 64);
                bool up = ((lane & k) == 0);
                bool lower = ((lane & d) == 0);
                v0 = (lower == up) ? min(v0, w0) : max(v0, w0);
            }
        }
        if (lane < len) esrc[lo + lane] = v0;
        return;
    }
    int v0 = (lane < len) ? esrc[lo + lane] : INF;
    int v1 = (64 + lane < len) ? esrc[lo + 64 + lane] : INF;
#pragma unroll
    for (int k = 2; k <= 128; k <<= 1) {
#pragma unroll
        for (int d = 64; d > 0; d >>= 1) {
            if (d >= k) continue;
            if (d == 64) {
                int a = min(v0, v1), b = max(v0, v1);
                v0 = a; v1 = b;
            } else {
                int w0 = __shfl_xor(v0, d, 64);
                int w1 = __shfl_xor(v1, d, 64);
                bool up0 = ((lane & k) == 0);
                bool up1 = (((64 + lane) & k) == 0);
                bool lower = ((lane & d) == 0);
                v0 = (lower == up0) ? min(v0, w0) : max(v0, w0);
                v1 = (lower == up1) ? min(v1, w1) : max(v1, w1);
            }
        }
    }
    if (lane < len) esrc[lo + lane] = v0;
    if (64 + lane < len) esrc[lo + 64 + lane] = v1;
}

// ---------- 5. fused: per-bucket src count -> out_norm + scale bucket's features ----------
__global__ void k_count_scale(const unsigned short* __restrict__ keys,
                              const int* __restrict__ gbaseB,
                              const float4* __restrict__ x4, float* __restrict__ out_norm,
                              uint2* __restrict__ xs) {
    __shared__ int hist[256];
    __shared__ float onl[BSZ];
    int b = blockIdx.x, t = threadIdx.x;
    int node0 = b * BSZ;
    int bstart = gbaseB[b], bend = gbaseB[b + 1];
    if (t < 256) hist[t] = 0;
    __syncthreads();
    for (int i = bstart + t; i < bend; i += 512)
        atomicAdd(&hist[keys[i]], 1);
    __syncthreads();
    if (t < BSZ) {
        float on = rsqrtf((float)max(hist[t], 1));
        onl[t] = on;
        out_norm[node0 + t] = on;
    }
    __syncthreads();
    // scale this bucket's 250 x 128 features: xs = bf16(x * out_norm)
    size_t base4 = (size_t)node0 * 32;
    for (int i = t; i < BSZ * 32; i += 512) {
        float on = onl[i >> 5];
        float4 v = x4[base4 + i];
        uint2 o;
        o.x = pack2(v.x * on, v.y * on);
        o.y = pack2(v.z * on, v.w * on);
        xs[base4 + i] = o;
    }
}

// ---------- 7. merged weight transpose + bf16 cast (all four weights) ----------
__global__ void k_transpose4(const float* __restrict__ w1, const float* __restrict__ w2,
                             const float* __restrict__ wm1, const float* __restrict__ wm2,
                             unsigned short* __restrict__ t1, unsigned short* __restrict__ t2,
                             unsigned short* __restrict__ tm1, unsigned short* __restrict__ tm2) {
    int i = blockIdx.x * blockDim.x + threadIdx.x;
    const float* w; unsigned short* t; int N, idx;
    if (i < 16384)       { w = w1;  t = t1;  N = 128; idx = i; }
    else if (i < 32768)  { w = w2;  t = t2;  N = 128; idx = i - 16384; }
    else if (i < 65536)  { w = wm1; t = tm1; N = 256; idx = i - 32768; }
    else if (i < 81920)  { w = wm2; t = tm2; N = 64;  idx = i - 65536; }
    else return;
    int K = (i < 65536) ? 128 : 256;
    int k = idx / N, n = idx - k * N;
    t[(size_t)n * K + k] = f2b(w[idx]);
}

// ---------- aggregate inner body: verified 4-deep unroll (VGPR-safe at 64-cap) ----------
// Per-lane summation order strictly ascending k -> bit-identical results.
// NOTE (round 3 lesson): 8-deep unroll under __launch_bounds__(256,8) (64 VGPR cap)
// spills the gather payloads to scratch: WRITE_SIZE 25->316 MB, k_conv 103->296 µs.
// Keep this at 4-deep unless launch bounds are relaxed.
#define AGG_ADD(p)                                                              \
        a0 += b2f_lo(p.x); a1 += b2f_hi(p.x);                                   \
        a2 += b2f_lo(p.y); a3 += b2f_hi(p.y);                                   \
        a4 += b2f_lo(p.z); a5 += b2f_hi(p.z);                                   \
        a6 += b2f_lo(p.w); a7 += b2f_hi(p.w);

#define AGG_NODE_BODY(node)                                                     \
    int lo = offsets[node], hi = offsets[node + 1];                             \
    float a0 = 0.f, a1 = 0.f, a2 = 0.f, a3 = 0.f,                               \
          a4 = 0.f, a5 = 0.f, a6 = 0.f, a7 = 0.f;                               \
    int k = lo + g;                                                             \
    for (; k + 12 < hi; k += 16) {                                              \
        int s0 = esrc[k];                                                       \
        int s1 = esrc[k + 4];                                                   \
        int s2 = esrc[k + 8];                                                   \
        int s3 = esrc[k + 12];                                                  \
        uint4 p0 = feat[(size_t)s0 * 16 + c];                                   \
        uint4 p1 = feat[(size_t)s1 * 16 + c];                                   \
        uint4 p2 = feat[(size_t)s2 * 16 + c];                                   \
        uint4 p3 = feat[(size_t)s3 * 16 + c];                                   \
        AGG_ADD(p0) AGG_ADD(p1) AGG_ADD(p2) AGG_ADD(p3)                         \
    }                                                                           \
    for (; k < hi; k += 4) {                                                    \
        int s = esrc[k];                                                        \
        uint4 p = feat[(size_t)s * 16 + c];                                     \
        AGG_ADD(p)                                                              \
    }                                                                           \
    a0 += __shfl_xor(a0, 16, 64); a0 += __shfl_xor(a0, 32, 64);                 \
    a1 += __shfl_xor(a1, 16, 64); a1 += __shfl_xor(a1, 32, 64);                 \
    a2 += __shfl_xor(a2, 16, 64); a2 += __shfl_xor(a2, 32, 64);                 \
    a3 += __shfl_xor(a3, 16, 64); a3 += __shfl_xor(a3, 32, 64);                 \
    a4 += __shfl_xor(a4, 16, 64); a4 += __shfl_xor(a4, 32, 64);                 \
    a5 += __shfl_xor(a5, 16, 64); a5 += __shfl_xor(a5, 32, 64);                 \
    a6 += __shfl_xor(a6, 16, 64); a6 += __shfl_xor(a6, 32, 64);                 \
    a7 += __shfl_xor(a7, 16, 64); a7 += __shfl_xor(a7, 32, 64);

// ---------- 8. fused conv1: aggregate(32 nodes) -> LDS -> MFMA GEMM -> relu*scale ----------
// LDS 8704 B, 4 waves/block -> 8 blocks/CU. Epilogue staged through LDS (A dead
// after MFMA reads) -> coalesced 16B row dumps instead of 16 scattered 2B stores.
__global__ __launch_bounds__(256, 8)
void k_conv(const int* __restrict__ offsets, const int* __restrict__ esrc,
            const uint4* __restrict__ feat, const float* __restrict__ in_norm,
            const unsigned short* __restrict__ WT, const float* __restrict__ bias,
            const float* __restrict__ row_scale, unsigned short* __restrict__ C,
            int N) {
    __shared__ __align__(16) unsigned short A[32][136];   // 272B row stride
    int wv = threadIdx.x >> 6, lane = threadIdx.x & 63;
    int row0 = blockIdx.x * 32;
    int g = lane >> 4, c = lane & 15;

    // phase A: aggregate
    for (int i = 0; i < 8; ++i) {
        int nl = wv * 8 + i;
        int node = row0 + nl;
        AGG_NODE_BODY(node)
        if (g == 0) {
            float inn = in_norm[node];
            uint4 o;
            o.x = pack2(a0 * inn, a1 * inn);
            o.y = pack2(a2 * inn, a3 * inn);
            o.z = pack2(a4 * inn, a5 * inn);
            o.w = pack2(a6 * inn, a7 * inn);
            *(uint4*)&A[nl][c * 8] = o;
        }
    }
    __syncthreads();

    // phase B: GEMM 32x128 tile, wave covers cols wv*32 .. wv*32+31
    int m = lane & 15, q = lane >> 4;
    const unsigned short* b0 = WT + (size_t)(wv * 32 + m) * 128 + q * 8;
    const unsigned short* b1 = b0 + (size_t)16 * 128;
    f32x4 acc00 = {0.f, 0.f, 0.f, 0.f}, acc10 = {0.f, 0.f, 0.f, 0.f};
    f32x4 acc01 = {0.f, 0.f, 0.f, 0.f}, acc11 = {0.f, 0.f, 0.f, 0.f};
#pragma unroll
    for (int k = 0; k < 128; k += 32) {
        bf16x8 bf0 = *(const bf16x8*)(b0 + k);
        bf16x8 bf1 = *(const bf16x8*)(b1 + k);
        bf16x8 af0 = *(const bf16x8*)&A[m][q * 8 + k];
        bf16x8 af1 = *(const bf16x8*)&A[16 + m][q * 8 + k];
        acc00 = __builtin_amdgcn_mfma_f32_16x16x32_bf16(af0, bf0, acc00, 0, 0, 0);
        acc10 = __builtin_amdgcn_mfma_f32_16x16x32_bf16(af1, bf0, acc10, 0, 0, 0);
        acc01 = __builtin_amdgcn_mfma_f32_16x16x32_bf16(af0, bf1, acc01, 0, 0, 0);
        acc11 = __builtin_amdgcn_mfma_f32_16x16x32_bf16(af1, bf1, acc11, 0, 0, 0);
    }
    __syncthreads();   // all A reads complete -> A reusable as C-staging tile

    int col0 = wv * 32 + m;
    int col1 = col0 + 16;
    float bc0 = bias[col0], bc1 = bias[col1];
#pragma unroll
    for (int r = 0; r < 4; r++) {
        int rl = q * 4 + r;
        int rr = row0 + rl, rr1 = rr + 16;
        float v00 = fmaxf(acc00[r] + bc0, 0.f);
        float v10 = fmaxf(acc10[r] + bc0, 0.f);
        float v01 = fmaxf(acc01[r] + bc1, 0.f);
        float v11 = fmaxf(acc11[r] + bc1, 0.f);
        float s0 = row_scale[rr], s1 = row_scale[rr1];
        v00 *= s0; v01 *= s0; v10 *= s1; v11 *= s1;
        A[rl][col0]      = f2b(v00);
        A[rl][col1]      = f2b(v01);
        A[rl + 16][col0] = f2b(v10);
        A[rl + 16][col1] = f2b(v11);
    }
    __syncthreads();
    // coalesced dump: 32 rows x 256B
#pragma unroll
    for (int it = 0; it < 2; ++it) {
        int idx = it * 256 + (int)threadIdx.x;     // 512 x 16B = 8192B
        int row = idx >> 4, seg = idx & 15;
        uint4 v = *(const uint4*)&A[row][seg * 8];
        *(uint4*)&C[(size_t)(row0 + row) * 128 + seg * 8] = v;
    }
}

// ---------- 9. fused conv2 + MLP, LDS 17408 B -> 8 blocks/CU ----------
// Regions: H1[32][136] at 0; region2 (A / H2 half-buffer, both [32][136]) at 4352.
// MLP2 K-loop split into two 128-halves (C0,D0,C1,D1); accumulator in registers,
// k-ascending order preserved -> bit-identical to the single-pass version.
// Final out staged via LDS (entire smem dead after phase D) -> coalesced f32 rows.
__global__ __launch_bounds__(256, 8)
void k_conv2_mlp(const int* __restrict__ offsets, const int* __restrict__ esrc,
                 const uint4* __restrict__ feat, const float* __restrict__ in_norm,
                 const unsigned short* __restrict__ WT2, const float* __restrict__ b2,
                 const unsigned short* __restrict__ WTM1, const float* __restrict__ bm1,
                 const unsigned short* __restrict__ WTM2, const float* __restrict__ bm2,
                 float* __restrict__ out, int N) {
    __shared__ __align__(16) unsigned short smem[8704];       // 17408 B
    unsigned short (*H1)[136] = (unsigned short(*)[136])(smem);
    unsigned short (*A)[136]  = (unsigned short(*)[136])(smem + 4352);
    unsigned short (*H2)[136] = (unsigned short(*)[136])(smem + 4352);  // alias of A

    int wv = threadIdx.x >> 6, lane = threadIdx.x & 63;
    int row0 = blockIdx.x * 32;
    int g = lane >> 4, c = lane & 15;

    // phase A: aggregate 32 nodes -> A
    for (int i = 0; i < 8; ++i) {
        int nl = wv * 8 + i;
        int node = row0 + nl;
        AGG_NODE_BODY(node)
        if (g == 0) {
            float inn = in_norm[node];
            uint4 o;
            o.x = pack2(a0 * inn, a1 * inn);
            o.y = pack2(a2 * inn, a3 * inn);
            o.z = pack2(a4 * inn, a5 * inn);
            o.w = pack2(a6 * inn, a7 * inn);
            *(uint4*)&A[nl][c * 8] = o;
        }
    }
    __syncthreads();

    int m = lane & 15, q = lane >> 4;

    // phase B: h2 = relu(A @ w2 + b2) -> H1 (H1 disjoint from A: no extra barrier)
    {
        const unsigned short* bb0 = WT2 + (size_t)(wv * 32 + m) * 128 + q * 8;
        const unsigned short* bb1 = bb0 + (size_t)16 * 128;
        f32x4 acc00 = {0.f, 0.f, 0.f, 0.f}, acc10 = {0.f, 0.f, 0.f, 0.f};
        f32x4 acc01 = {0.f, 0.f, 0.f, 0.f}, acc11 = {0.f, 0.f, 0.f, 0.f};
#pragma unroll
        for (int k = 0; k < 128; k += 32) {
            bf16x8 bf0 = *(const bf16x8*)(bb0 + k);
            bf16x8 bf1 = *(const bf16x8*)(bb1 + k);
            bf16x8 af0 = *(const bf16x8*)&A[m][q * 8 + k];
            bf16x8 af1 = *(const bf16x8*)&A[16 + m][q * 8 + k];
            acc00 = __builtin_amdgcn_mfma_f32_16x16x32_bf16(af0, bf0, acc00, 0, 0, 0);
            acc10 = __builtin_amdgcn_mfma_f32_16x16x32_bf16(af1, bf0, acc10, 0, 0, 0);
            acc01 = __builtin_amdgcn_mfma_f32_16x16x32_bf16(af0, bf1, acc01, 0, 0, 0);
            acc11 = __builtin_amdgcn_mfma_f32_16x16x32_bf16(af1, bf1, acc11, 0, 0, 0);
        }
        int col0 = wv * 32 + m;
        int col1 = col0 + 16;
        float bc0 = b2[col0], bc1 = b2[col1];
#pragma unroll
        for (int r = 0; r < 4; r++) {
            int rl = q * 4 + r;
            H1[rl][col0]      = f2b(fmaxf(acc00[r] + bc0, 0.f));
            H1[rl][col1]      = f2b(fmaxf(acc01[r] + bc1, 0.f));
            H1[rl + 16][col0] = f2b(fmaxf(acc10[r] + bc0, 0.f));
            H1[rl + 16][col1] = f2b(fmaxf(acc11[r] + bc1, 0.f));
        }
    }
    __syncthreads();   // H1 complete; all A reads done (H2 may now overwrite A)

    // phases C/D x2: mlp1 half -> H2, then mlp2 partial-K accumulate
    f32x4 macc0 = {0.f, 0.f, 0.f, 0.f}, macc1 = {0.f, 0.f, 0.f, 0.f};
    int colo = wv * 16 + m;
    const unsigned short* bp2 = WTM2 + (size_t)colo * 256 + q * 8;
#pragma unroll
    for (int half = 0; half < 2; ++half) {
        // C: mlp1 columns [half*128, half*128+128), full K=128 per column
#pragma unroll
        for (int cb = 0; cb < 2; cb++) {
            int colh = half * 128 + wv * 32 + cb * 16 + m;
            const unsigned short* bp = WTM1 + (size_t)colh * 128 + q * 8;
            f32x4 acc0 = {0.f, 0.f, 0.f, 0.f};
            f32x4 acc1 = {0.f, 0.f, 0.f, 0.f};
#pragma unroll
            for (int s = 0; s < 4; s++) {
                bf16x8 bfr = *(const bf16x8*)(bp + s * 32);
                bf16x8 ha0 = *(const bf16x8*)&H1[m][s * 32 + q * 8];
                bf16x8 ha1 = *(const bf16x8*)&H1[m + 16][s * 32 + q * 8];
                acc0 = __builtin_amdgcn_mfma_f32_16x16x32_bf16(ha0, bfr, acc0, 0, 0, 0);
                acc1 = __builtin_amdgcn_mfma_f32_16x16x32_bf16(ha1, bfr, acc1, 0, 0, 0);
            }
            float bc = bm1[colh];
            int cl = colh & 127;
#pragma unroll
            for (int r = 0; r < 4; r++) {
                H2[q * 4 + r][cl]      = f2b(fmaxf(acc0[r] + bc, 0.f));
                H2[q * 4 + r + 16][cl] = f2b(fmaxf(acc1[r] + bc, 0.f));
            }
        }
        __syncthreads();
        // D: mlp2 K-slice [half*128, half*128+128), k-ascending
#pragma unroll
        for (int s = 0; s < 4; s++) {
            bf16x8 bfr = *(const bf16x8*)(bp2 + half * 128 + s * 32);
            bf16x8 ha0 = *(const bf16x8*)&H2[m][s * 32 + q * 8];
            bf16x8 ha1 = *(const bf16x8*)&H2[m + 16][s * 32 + q * 8];
            macc0 = __builtin_amdgcn_mfma_f32_16x16x32_bf16(ha0, bfr, macc0, 0, 0, 0);
            macc1 = __builtin_amdgcn_mfma_f32_16x16x32_bf16(ha1, bfr, macc1, 0, 0, 0);
        }
        __syncthreads();   // H2 reads done before next half overwrites / epilogue
    }

    // epilogue: stage 32x64 f32 tile in LDS (all smem dead now), coalesced dump
    float* OS = (float*)smem;                     // [32][64], 8192 B
    float bc = bm2[colo];
#pragma unroll
    for (int r = 0; r < 4; r++) {
        OS[(q * 4 + r) * 64 + colo]        = macc0[r] + bc;
        OS[(q * 4 + r + 16) * 64 + colo]   = macc1[r] + bc;
    }
    __syncthreads();
#pragma unroll
    for (int it = 0; it < 2; ++it) {
        int idx = it * 256 + (int)threadIdx.x;    // 512 x 16B = 8192B
        int row = idx >> 4, seg = idx & 15;
        float4 v = *(const float4*)&OS[row * 64 + seg * 4];
        *(float4*)&out[(size_t)(row0 + row) * 64 + seg * 4] = v;
    }
}

extern "C" void kernel_launch(void* const* d_in, const int* in_sizes, int n_in,
                              void* d_out, int out_size, void* d_ws, size_t ws_size,
                              hipStream_t stream) {
    const float* x    = (const float*)d_in[0];
    const int*   src  = (const int*)d_in[1];
    const int*   dst  = (const int*)d_in[2];
    const float* w1   = (const float*)d_in[3];
    const float* b1   = (const float*)d_in[4];
    const float* w2   = (const float*)d_in[5];
    const float* b2   = (const float*)d_in[6];
    const float* wm1  = (const float*)d_in[7];
    const float* bm1  = (const float*)d_in[8];
    const float* wm2  = (const float*)d_in[9];
    const float* bm2  = (const float*)d_in[10];

    const int N = N_NODES;
    const int E = N_EDGES;

    char* p = (char*)d_ws;
    auto alloc = [&](size_t bytes) -> void* {
        void* r = (void*)p;
        p += (bytes + 255) & ~(size_t)255;
        return r;
    };
    int*   gcntA   = (int*)alloc((NBUCK + 1) * 4);   // contiguous with gcntB: one memset
    int*   gcntB   = (int*)alloc((NBUCK + 1) * 4);
    int*   gbaseA  = (int*)alloc((NBUCK + 1) * 4);
    int*   gbaseB  = (int*)alloc((NBUCK + 1) * 4);
    int*   gcurA   = (int*)alloc((NBUCK + 1) * 4);
    int*   gcurB   = (int*)alloc((NBUCK + 1) * 4);
    int*   offsets = (int*)alloc((size_t)(N + 1) * 4);
    float* out_norm = (float*)alloc((size_t)N * 4);
    float* in_norm  = (float*)alloc((size_t)N * 4);
    int*   esrc     = (int*)alloc((size_t)E * 4);
    unsigned int* bufA = (unsigned int*)alloc((size_t)N * 128 * 2);  // xs
    unsigned int* bufB = (unsigned int*)alloc((size_t)N * 128 * 2);  // pairs (build only)
    unsigned int* bufC = (unsigned int*)alloc((size_t)N * 128 * 2);  // keysB, then h1
    unsigned short* wt1  = (unsigned short*)alloc(128 * 128 * 2);
    unsigned short* wt2  = (unsigned short*)alloc(128 * 128 * 2);
    unsigned short* wtm1 = (unsigned short*)alloc(256 * 128 * 2);
    unsigned short* wtm2 = (unsigned short*)alloc(64 * 256 * 2);
    (void)ws_size; (void)n_in; (void)in_sizes; (void)out_size;

    unsigned*       pairs = (unsigned*)bufB;       // packed (dloc<<17|src), dead after csr
    unsigned short* keysB = (unsigned short*)bufC; // bucket-local src ids, dead after count

    hipMemsetAsync(gcntA, 0, (size_t)((char*)gcntB - (char*)gcntA) + NBUCK * 4, stream);

    const int TB = 256;
    // CSR build via two-level LDS counting sort (no per-edge global atomics)
    k_hist2<<<dim3(256), dim3(TB), 0, stream>>>(src, dst, gcntA, gcntB, E);
    k_scan_coarse<<<dim3(1), dim3(512), 0, stream>>>(gcntA, gcntB, gbaseA, gbaseB,
                                                     gcurA, gcurB, offsets);
    k_scatter<<<dim3(256), dim3(TB), 0, stream>>>(src, dst, gcurA, gcurB, pairs, keysB, E);
    k_csr_bucket<<<dim3(NBUCK), dim3(512), 0, stream>>>(pairs, gbaseA, offsets, in_norm, esrc);
    // canonicalize segment order (wave bitonic) -> bit-deterministic sums
    k_sortwave<<<dim3(N / 4), dim3(TB), 0, stream>>>(offsets, esrc, N);
    // out_norm from src counts + xs = bf16(x * out_norm), fused per bucket
    k_count_scale<<<dim3(NBUCK), dim3(512), 0, stream>>>(
        keysB, gbaseB, (const float4*)x, out_norm, (uint2*)bufA);

    // all weight transposes (fp32 -> bf16) in one launch
    k_transpose4<<<dim3(320), dim3(TB), 0, stream>>>(w1, w2, wm1, wm2, wt1, wt2, wtm1, wtm2);

    // conv1: fused aggregate + gemm(w1) + relu + fold out_norm (bufA -> bufC)
    k_conv<<<dim3(N / 32), dim3(TB), 0, stream>>>(
        offsets, esrc, (const uint4*)bufA, in_norm, wt1, b1, out_norm,
        (unsigned short*)bufC, N);

    // conv2 + MLP: fused aggregate + gemm(w2) + mlp1 + mlp2 (bufC -> d_out)
    k_conv2_mlp<<<dim3(N / 32), dim3(TB), 0, stream>>>(
        offsets, esrc, (const uint4*)bufC, in_norm, wt2, b2, wtm1, bm1, wtm2, bm2,
        (float*)d_out, N);
}

// Round 7
// 525.945 us; speedup vs baseline: 1.4916x; 1.0507x over previous
//
#include <hip/hip_runtime.h>
#include <hip/hip_bf16.h>
#include <cstdint>

// ---------- bf16 helpers (raw ushort representation) ----------
__device__ __forceinline__ unsigned short f2b(float f) {
    union { float f; unsigned int i; } v; v.f = f;
    unsigned int i = v.i;
    unsigned int r = (i + 0x7FFFu + ((i >> 16) & 1u)) >> 16;   // RNE, finite inputs
    return (unsigned short)r;
}
__device__ __forceinline__ float b2f_lo(unsigned int p) {
    union { unsigned int i; float f; } v; v.i = p << 16; return v.f;
}
__device__ __forceinline__ float b2f_hi(unsigned int p) {
    union { unsigned int i; float f; } v; v.i = p & 0xFFFF0000u; return v.f;
}
__device__ __forceinline__ unsigned int pack2(float a, float b) {
    return (unsigned int)f2b(a) | ((unsigned int)f2b(b) << 16);
}

typedef __attribute__((__ext_vector_type__(8))) __bf16 bf16x8;
typedef __attribute__((__ext_vector_type__(4))) float  f32x4;

#define N_NODES 100000
#define N_EDGES 3200000
#define NBUCK   400        // coarse buckets (400 blocks -> full 256-CU coverage)
#define BSZ     250        // nodes per bucket (400*250 = 100000)
#define NCHUNK  256        // edge chunks (one per hist/scatter block)
#define CHUNK   12500      // E / NCHUNK
#define BCAP    9216       // per-bucket edge capacity: mean 8000, sigma 89 -> 13.6 sigma

// ---------- 1. coarse histograms; per-block counts persisted for k_scatter ----------
__global__ void k_hist2(const int* __restrict__ src, const int* __restrict__ dst,
                        int* __restrict__ gcntA, int* __restrict__ gcntB,
                        int* __restrict__ blkA, int* __restrict__ blkB, int E) {
    __shared__ int hA[NBUCK], hB[NBUCK];
    int t = threadIdx.x, b = blockIdx.x;
    int lo = b * CHUNK, hi = min(lo + CHUNK, E);
    for (int j = t; j < NBUCK; j += 256) { hA[j] = 0; hB[j] = 0; }
    __syncthreads();
    for (int i = lo + t; i < hi; i += 256) {
        atomicAdd(&hA[dst[i] / BSZ], 1);
        atomicAdd(&hB[src[i] / BSZ], 1);
    }
    __syncthreads();
    for (int j = t; j < NBUCK; j += 256) {
        blkA[b * NBUCK + j] = hA[j];
        blkB[b * NBUCK + j] = hB[j];
        if (hA[j]) atomicAdd(&gcntA[j], hA[j]);
        if (hB[j]) atomicAdd(&gcntB[j], hB[j]);
    }
}

// ---------- 2. scan coarse counts -> bucket bases + cursors (512 threads) ----------
__global__ void k_scan_coarse(const int* __restrict__ gcntA, const int* __restrict__ gcntB,
                              int* __restrict__ gbaseA, int* __restrict__ gbaseB,
                              int* __restrict__ gcurA, int* __restrict__ gcurB,
                              int* __restrict__ offsets) {
    __shared__ int pA[512], pB[512];
    int t = threadIdx.x;
    int vA = (t < NBUCK) ? gcntA[t] : 0;
    int vB = (t < NBUCK) ? gcntB[t] : 0;
    pA[t] = vA; pB[t] = vB;
    __syncthreads();
    for (int d = 1; d < 512; d <<= 1) {
        int a = (t >= d) ? pA[t - d] : 0;
        int b = (t >= d) ? pB[t - d] : 0;
        __syncthreads();
        pA[t] += a; pB[t] += b;
        __syncthreads();
    }
    if (t < NBUCK) {
        gbaseA[t] = pA[t] - vA; gcurA[t] = pA[t] - vA;
        gbaseB[t] = pB[t] - vB; gcurB[t] = pB[t] - vB;
    }
    if (t == 511) {
        gbaseA[NBUCK] = pA[511];
        gbaseB[NBUCK] = pB[511];
        offsets[N_NODES] = pA[511];   // == E
    }
}

// ---------- 3. scatter using persisted histograms (single edge pass) ----------
__global__ void k_scatter(const int* __restrict__ src, const int* __restrict__ dst,
                          int* __restrict__ gcurA, int* __restrict__ gcurB,
                          const int* __restrict__ blkA, const int* __restrict__ blkB,
                          unsigned* __restrict__ pairs, unsigned short* __restrict__ keysB,
                          int E) {
    __shared__ int baA[NBUCK], baB[NBUCK], lcA[NBUCK], lcB[NBUCK];
    int t = threadIdx.x, b = blockIdx.x;
    int lo = b * CHUNK, hi = min(lo + CHUNK, E);
    for (int j = t; j < NBUCK; j += 256) {
        int hA = blkA[b * NBUCK + j];
        baA[j] = hA ? atomicAdd(&gcurA[j], hA) : 0;
        lcA[j] = 0;
        int hB = blkB[b * NBUCK + j];
        baB[j] = hB ? atomicAdd(&gcurB[j], hB) : 0;
        lcB[j] = 0;
    }
    __syncthreads();
    for (int i = lo + t; i < hi; i += 256) {
        int s = src[i], d = dst[i];
        int bA = d / BSZ;
        int l  = atomicAdd(&lcA[bA], 1);
        pairs[baA[bA] + l] = ((unsigned)(d - bA * BSZ) << 17) | (unsigned)s;
        int bB = s / BSZ;
        int l2 = atomicAdd(&lcB[bB], 1);
        keysB[baB[bB] + l2] = (unsigned short)(s - bB * BSZ);
    }
}

// ---------- 4. per-bucket CSR + in-LDS segment sort (replaces csr_bucket+sortwave) ----
// esrc for the whole bucket built in LDS, each node's segment sorted with the SAME
// bitonic networks as the old k_sortwave (64/128-wide, 128 cap) -> identical esrc.
__global__ __launch_bounds__(512)
void k_csr_sort(const unsigned* __restrict__ pairs, const int* __restrict__ gbaseA,
                int* __restrict__ offsets, float* __restrict__ in_norm,
                int* __restrict__ esrc) {
    __shared__ int el[BCAP];
    __shared__ int hist[256], scan[256], curs[256];
    int b = blockIdx.x, t = threadIdx.x;
    int node0 = b * BSZ;
    int bstart = gbaseA[b], bend = gbaseA[b + 1];
    int cnt = bend - bstart;
    if (t < 256) hist[t] = 0;
    __syncthreads();
    for (int i = bstart + t; i < bend; i += 512)
        atomicAdd(&hist[pairs[i] >> 17], 1);
    __syncthreads();
    if (t < 256) scan[t] = hist[t];
    __syncthreads();
    for (int d = 1; d < 256; d <<= 1) {
        int v = (t < 256 && t >= d) ? scan[t - d] : 0;
        __syncthreads();
        if (t < 256) scan[t] += v;
        __syncthreads();
    }
    if (t < BSZ) {
        int excl = scan[t] - hist[t];
        offsets[node0 + t] = bstart + excl;
        in_norm[node0 + t] = rsqrtf((float)max(hist[t], 1));
        curs[t] = excl;
    }
    __syncthreads();
    // scatter bucket edges into LDS at bucket-local slots
    for (int i = bstart + t; i < bend; i += 512) {
        unsigned p = pairs[i];
        int d = (int)(p >> 17);
        int l = atomicAdd(&curs[d], 1);
        el[l] = (int)(p & 0x1FFFFu);
    }
    __syncthreads();
    // per-node segment sort: 8 waves round-robin over nodes; same networks as before
    int wv = t >> 6, lane = t & 63;
    const int INF = 0x7FFFFFFF;
    for (int n = wv; n < BSZ; n += 8) {
        int len = hist[n];
        if (len <= 1) continue;
        int base = scan[n] - len;
        if (len <= 64) {
            int v0 = (lane < len) ? el[base + lane] : INF;
#pragma unroll
            for (int k = 2; k <= 64; k <<= 1) {
#pragma unroll
                for (int d = 32; d > 0; d >>= 1) {
                    if (d >= k) continue;
                    int w0 = __shfl_xor(v0, d, 64);
                    bool up = ((lane & k) == 0);
                    bool lower = ((lane & d) == 0);
                    v0 = (lower == up) ? min(v0, w0) : max(v0, w0);
                }
            }
            if (lane < len) el[base + lane] = v0;
        } else {
            int v0 = (lane < len) ? el[base + lane] : INF;
            int v1 = (64 + lane < len) ? el[base + 64 + lane] : INF;
#pragma unroll
            for (int k = 2; k <= 128; k <<= 1) {
#pragma unroll
                for (int d = 64; d > 0; d >>= 1) {
                    if (d >= k) continue;
                    if (d == 64) {
                        int a = min(v0, v1), bb = max(v0, v1);
                        v0 = a; v1 = bb;
                    } else {
                        int w0 = __shfl_xor(v0, d, 64);
                        int w1 = __shfl_xor(v1, d, 64);
                        bool up0 = ((lane & k) == 0);
                        bool up1 = (((64 + lane) & k) == 0);
                        bool lower = ((lane & d) == 0);
                        v0 = (lower == up0) ? min(v0, w0) : max(v0, w0);
                        v1 = (lower == up1) ? min(v1, w1) : max(v1, w1);
                    }
                }
            }
            if (lane < len) el[base + lane] = v0;
            if (64 + lane < len) el[base + 64 + lane] = v1;
        }
    }
    __syncthreads();
    // coalesced dump
    for (int i = t; i < cnt; i += 512) esrc[bstart + i] = el[i];
}

// ---------- 5. fused: src count -> out_norm + feature scale + weight transposes ----------
__global__ __launch_bounds__(512)
void k_count_scale(const unsigned short* __restrict__ keys,
                   const int* __restrict__ gbaseB,
                   const float4* __restrict__ x4, float* __restrict__ out_norm,
                   uint2* __restrict__ xs,
                   const float* __restrict__ w1, const float* __restrict__ w2,
                   const float* __restrict__ wm1, const float* __restrict__ wm2,
                   unsigned short* __restrict__ t1, unsigned short* __restrict__ t2,
                   unsigned short* __restrict__ tm1, unsigned short* __restrict__ tm2) {
    // independent tail work first (overlaps the histogram's memory latency):
    // all four weight transposes, 81920 elems spread over the grid
    {
        int gid = blockIdx.x * 512 + threadIdx.x;
        if (gid < 81920) {
            const float* w; unsigned short* tt; int Nn, idx;
            if (gid < 16384)       { w = w1;  tt = t1;  Nn = 128; idx = gid; }
            else if (gid < 32768)  { w = w2;  tt = t2;  Nn = 128; idx = gid - 16384; }
            else if (gid < 65536)  { w = wm1; tt = tm1; Nn = 256; idx = gid - 32768; }
            else                   { w = wm2; tt = tm2; Nn = 64;  idx = gid - 65536; }
            int K = (gid < 65536) ? 128 : 256;
            int k = idx / Nn, n = idx - k * Nn;
            tt[(size_t)n * K + k] = f2b(w[idx]);
        }
    }
    __shared__ int hist[256];
    __shared__ float onl[BSZ];
    int b = blockIdx.x, t = threadIdx.x;
    int node0 = b * BSZ;
    int bstart = gbaseB[b], bend = gbaseB[b + 1];
    if (t < 256) hist[t] = 0;
    __syncthreads();
    for (int i = bstart + t; i < bend; i += 512)
        atomicAdd(&hist[keys[i]], 1);
    __syncthreads();
    if (t < BSZ) {
        float on = rsqrtf((float)max(hist[t], 1));
        onl[t] = on;
        out_norm[node0 + t] = on;
    }
    __syncthreads();
    // scale this bucket's 250 x 128 features: xs = bf16(x * out_norm)
    size_t base4 = (size_t)node0 * 32;
    for (int i = t; i < BSZ * 32; i += 512) {
        float on = onl[i >> 5];
        float4 v = x4[base4 + i];
        uint2 o;
        o.x = pack2(v.x * on, v.y * on);
        o.y = pack2(v.z * on, v.w * on);
        xs[base4 + i] = o;
    }
}

// ---------- aggregate inner body: verified 4-deep unroll (VGPR-safe at 64-cap) ----------
// Per-lane summation order strictly ascending k -> bit-identical results.
// NOTE (round 3 lesson): 8-deep unroll under __launch_bounds__(256,8) (64 VGPR cap)
// spills the gather payloads to scratch: WRITE_SIZE 25->316 MB, k_conv 103->296 µs.
// Keep this at 4-deep unless launch bounds are relaxed.
#define AGG_ADD(p)                                                              \
        a0 += b2f_lo(p.x); a1 += b2f_hi(p.x);                                   \
        a2 += b2f_lo(p.y); a3 += b2f_hi(p.y);                                   \
        a4 += b2f_lo(p.z); a5 += b2f_hi(p.z);                                   \
        a6 += b2f_lo(p.w); a7 += b2f_hi(p.w);

#define AGG_NODE_BODY(node)                                                     \
    int lo = offsets[node], hi = offsets[node + 1];                             \
    float a0 = 0.f, a1 = 0.f, a2 = 0.f, a3 = 0.f,                               \
          a4 = 0.f, a5 = 0.f, a6 = 0.f, a7 = 0.f;                               \
    int k = lo + g;                                                             \
    for (; k + 12 < hi; k += 16) {                                              \
        int s0 = esrc[k];                                                       \
        int s1 = esrc[k + 4];                                                   \
        int s2 = esrc[k + 8];                                                   \
        int s3 = esrc[k + 12];                                                  \
        uint4 p0 = feat[(size_t)s0 * 16 + c];                                   \
        uint4 p1 = feat[(size_t)s1 * 16 + c];                                   \
        uint4 p2 = feat[(size_t)s2 * 16 + c];                                   \
        uint4 p3 = feat[(size_t)s3 * 16 + c];                                   \
        AGG_ADD(p0) AGG_ADD(p1) AGG_ADD(p2) AGG_ADD(p3)                         \
    }                                                                           \
    for (; k < hi; k += 4) {                                                    \
        int s = esrc[k];                                                        \
        uint4 p = feat[(size_t)s * 16 + c];                                     \
        AGG_ADD(p)                                                              \
    }                                                                           \
    a0 += __shfl_xor(a0, 16, 64); a0 += __shfl_xor(a0, 32, 64);                 \
    a1 += __shfl_xor(a1, 16, 64); a1 += __shfl_xor(a1, 32, 64);                 \
    a2 += __shfl_xor(a2, 16, 64); a2 += __shfl_xor(a2, 32, 64);                 \
    a3 += __shfl_xor(a3, 16, 64); a3 += __shfl_xor(a3, 32, 64);                 \
    a4 += __shfl_xor(a4, 16, 64); a4 += __shfl_xor(a4, 32, 64);                 \
    a5 += __shfl_xor(a5, 16, 64); a5 += __shfl_xor(a5, 32, 64);                 \
    a6 += __shfl_xor(a6, 16, 64); a6 += __shfl_xor(a6, 32, 64);                 \
    a7 += __shfl_xor(a7, 16, 64); a7 += __shfl_xor(a7, 32, 64);

// ---------- 8. fused conv1: aggregate(32 nodes) -> LDS -> MFMA GEMM -> relu*scale ----------
// LDS 8704 B, 4 waves/block -> 8 blocks/CU. Epilogue staged through LDS (A dead
// after MFMA reads) -> coalesced 16B row dumps instead of 16 scattered 2B stores.
__global__ __launch_bounds__(256, 8)
void k_conv(const int* __restrict__ offsets, const int* __restrict__ esrc,
            const uint4* __restrict__ feat, const float* __restrict__ in_norm,
            const unsigned short* __restrict__ WT, const float* __restrict__ bias,
            const float* __restrict__ row_scale, unsigned short* __restrict__ C,
            int N) {
    __shared__ __align__(16) unsigned short A[32][136];   // 272B row stride
    int wv = threadIdx.x >> 6, lane = threadIdx.x & 63;
    int row0 = blockIdx.x * 32;
    int g = lane >> 4, c = lane & 15;

    // phase A: aggregate
    for (int i = 0; i < 8; ++i) {
        int nl = wv * 8 + i;
        int node = row0 + nl;
        AGG_NODE_BODY(node)
        if (g == 0) {
            float inn = in_norm[node];
            uint4 o;
            o.x = pack2(a0 * inn, a1 * inn);
            o.y = pack2(a2 * inn, a3 * inn);
            o.z = pack2(a4 * inn, a5 * inn);
            o.w = pack2(a6 * inn, a7 * inn);
            *(uint4*)&A[nl][c * 8] = o;
        }
    }
    __syncthreads();

    // phase B: GEMM 32x128 tile, wave covers cols wv*32 .. wv*32+31
    int m = lane & 15, q = lane >> 4;
    const unsigned short* b0 = WT + (size_t)(wv * 32 + m) * 128 + q * 8;
    const unsigned short* b1 = b0 + (size_t)16 * 128;
    f32x4 acc00 = {0.f, 0.f, 0.f, 0.f}, acc10 = {0.f, 0.f, 0.f, 0.f};
    f32x4 acc01 = {0.f, 0.f, 0.f, 0.f}, acc11 = {0.f, 0.f, 0.f, 0.f};
#pragma unroll
    for (int k = 0; k < 128; k += 32) {
        bf16x8 bf0 = *(const bf16x8*)(b0 + k);
        bf16x8 bf1 = *(const bf16x8*)(b1 + k);
        bf16x8 af0 = *(const bf16x8*)&A[m][q * 8 + k];
        bf16x8 af1 = *(const bf16x8*)&A[16 + m][q * 8 + k];
        acc00 = __builtin_amdgcn_mfma_f32_16x16x32_bf16(af0, bf0, acc00, 0, 0, 0);
        acc10 = __builtin_amdgcn_mfma_f32_16x16x32_bf16(af1, bf0, acc10, 0, 0, 0);
        acc01 = __builtin_amdgcn_mfma_f32_16x16x32_bf16(af0, bf1, acc01, 0, 0, 0);
        acc11 = __builtin_amdgcn_mfma_f32_16x16x32_bf16(af1, bf1, acc11, 0, 0, 0);
    }
    __syncthreads();   // all A reads complete -> A reusable as C-staging tile

    int col0 = wv * 32 + m;
    int col1 = col0 + 16;
    float bc0 = bias[col0], bc1 = bias[col1];
#pragma unroll
    for (int r = 0; r < 4; r++) {
        int rl = q * 4 + r;
        int rr = row0 + rl, rr1 = rr + 16;
        float v00 = fmaxf(acc00[r] + bc0, 0.f);
        float v10 = fmaxf(acc10[r] + bc0, 0.f);
        float v01 = fmaxf(acc01[r] + bc1, 0.f);
        float v11 = fmaxf(acc11[r] + bc1, 0.f);
        float s0 = row_scale[rr], s1 = row_scale[rr1];
        v00 *= s0; v01 *= s0; v10 *= s1; v11 *= s1;
        A[rl][col0]      = f2b(v00);
        A[rl][col1]      = f2b(v01);
        A[rl + 16][col0] = f2b(v10);
        A[rl + 16][col1] = f2b(v11);
    }
    __syncthreads();
    // coalesced dump: 32 rows x 256B
#pragma unroll
    for (int it = 0; it < 2; ++it) {
        int idx = it * 256 + (int)threadIdx.x;     // 512 x 16B = 8192B
        int row = idx >> 4, seg = idx & 15;
        uint4 v = *(const uint4*)&A[row][seg * 8];
        *(uint4*)&C[(size_t)(row0 + row) * 128 + seg * 8] = v;
    }
}

// ---------- 9. fused conv2 + MLP, LDS 17408 B -> 8 blocks/CU ----------
// Regions: H1[32][136] at 0; region2 (A / H2 half-buffer, both [32][136]) at 4352.
// MLP2 K-loop split into two 128-halves (C0,D0,C1,D1); accumulator in registers,
// k-ascending order preserved -> bit-identical to the single-pass version.
// Final out staged via LDS, coalesced nontemporal f32 rows (write-once data).
__global__ __launch_bounds__(256, 8)
void k_conv2_mlp(const int* __restrict__ offsets, const int* __restrict__ esrc,
                 const uint4* __restrict__ feat, const float* __restrict__ in_norm,
                 const unsigned short* __restrict__ WT2, const float* __restrict__ b2,
                 const unsigned short* __restrict__ WTM1, const float* __restrict__ bm1,
                 const unsigned short* __restrict__ WTM2, const float* __restrict__ bm2,
                 float* __restrict__ out, int N) {
    __shared__ __align__(16) unsigned short smem[8704];       // 17408 B
    unsigned short (*H1)[136] = (unsigned short(*)[136])(smem);
    unsigned short (*A)[136]  = (unsigned short(*)[136])(smem + 4352);
    unsigned short (*H2)[136] = (unsigned short(*)[136])(smem + 4352);  // alias of A

    int wv = threadIdx.x >> 6, lane = threadIdx.x & 63;
    int row0 = blockIdx.x * 32;
    int g = lane >> 4, c = lane & 15;

    // phase A: aggregate 32 nodes -> A
    for (int i = 0; i < 8; ++i) {
        int nl = wv * 8 + i;
        int node = row0 + nl;
        AGG_NODE_BODY(node)
        if (g == 0) {
            float inn = in_norm[node];
            uint4 o;
            o.x = pack2(a0 * inn, a1 * inn);
            o.y = pack2(a2 * inn, a3 * inn);
            o.z = pack2(a4 * inn, a5 * inn);
            o.w = pack2(a6 * inn, a7 * inn);
            *(uint4*)&A[nl][c * 8] = o;
        }
    }
    __syncthreads();

    int m = lane & 15, q = lane >> 4;

    // phase B: h2 = relu(A @ w2 + b2) -> H1 (H1 disjoint from A: no extra barrier)
    {
        const unsigned short* bb0 = WT2 + (size_t)(wv * 32 + m) * 128 + q * 8;
        const unsigned short* bb1 = bb0 + (size_t)16 * 128;
        f32x4 acc00 = {0.f, 0.f, 0.f, 0.f}, acc10 = {0.f, 0.f, 0.f, 0.f};
        f32x4 acc01 = {0.f, 0.f, 0.f, 0.f}, acc11 = {0.f, 0.f, 0.f, 0.f};
#pragma unroll
        for (int k = 0; k < 128; k += 32) {
            bf16x8 bf0 = *(const bf16x8*)(bb0 + k);
            bf16x8 bf1 = *(const bf16x8*)(bb1 + k);
            bf16x8 af0 = *(const bf16x8*)&A[m][q * 8 + k];
            bf16x8 af1 = *(const bf16x8*)&A[16 + m][q * 8 + k];
            acc00 = __builtin_amdgcn_mfma_f32_16x16x32_bf16(af0, bf0, acc00, 0, 0, 0);
            acc10 = __builtin_amdgcn_mfma_f32_16x16x32_bf16(af1, bf0, acc10, 0, 0, 0);
            acc01 = __builtin_amdgcn_mfma_f32_16x16x32_bf16(af0, bf1, acc01, 0, 0, 0);
            acc11 = __builtin_amdgcn_mfma_f32_16x16x32_bf16(af1, bf1, acc11, 0, 0, 0);
        }
        int col0 = wv * 32 + m;
        int col1 = col0 + 16;
        float bc0 = b2[col0], bc1 = b2[col1];
#pragma unroll
        for (int r = 0; r < 4; r++) {
            int rl = q * 4 + r;
            H1[rl][col0]      = f2b(fmaxf(acc00[r] + bc0, 0.f));
            H1[rl][col1]      = f2b(fmaxf(acc01[r] + bc1, 0.f));
            H1[rl + 16][col0] = f2b(fmaxf(acc10[r] + bc0, 0.f));
            H1[rl + 16][col1] = f2b(fmaxf(acc11[r] + bc1, 0.f));
        }
    }
    __syncthreads();   // H1 complete; all A reads done (H2 may now overwrite A)

    // phases C/D x2: mlp1 half -> H2, then mlp2 partial-K accumulate
    f32x4 macc0 = {0.f, 0.f, 0.f, 0.f}, macc1 = {0.f, 0.f, 0.f, 0.f};
    int colo = wv * 16 + m;
    const unsigned short* bp2 = WTM2 + (size_t)colo * 256 + q * 8;
#pragma unroll
    for (int half = 0; half < 2; ++half) {
        // C: mlp1 columns [half*128, half*128+128), full K=128 per column
#pragma unroll
        for (int cb = 0; cb < 2; cb++) {
            int colh = half * 128 + wv * 32 + cb * 16 + m;
            const unsigned short* bp = WTM1 + (size_t)colh * 128 + q * 8;
            f32x4 acc0 = {0.f, 0.f, 0.f, 0.f};
            f32x4 acc1 = {0.f, 0.f, 0.f, 0.f};
#pragma unroll
            for (int s = 0; s < 4; s++) {
                bf16x8 bfr = *(const bf16x8*)(bp + s * 32);
                bf16x8 ha0 = *(const bf16x8*)&H1[m][s * 32 + q * 8];
                bf16x8 ha1 = *(const bf16x8*)&H1[m + 16][s * 32 + q * 8];
                acc0 = __builtin_amdgcn_mfma_f32_16x16x32_bf16(ha0, bfr, acc0, 0, 0, 0);
                acc1 = __builtin_amdgcn_mfma_f32_16x16x32_bf16(ha1, bfr, acc1, 0, 0, 0);
            }
            float bc = bm1[colh];
            int cl = colh & 127;
#pragma unroll
            for (int r = 0; r < 4; r++) {
                H2[q * 4 + r][cl]      = f2b(fmaxf(acc0[r] + bc, 0.f));
                H2[q * 4 + r + 16][cl] = f2b(fmaxf(acc1[r] + bc, 0.f));
            }
        }
        __syncthreads();
        // D: mlp2 K-slice [half*128, half*128+128), k-ascending
#pragma unroll
        for (int s = 0; s < 4; s++) {
            bf16x8 bfr = *(const bf16x8*)(bp2 + half * 128 + s * 32);
            bf16x8 ha0 = *(const bf16x8*)&H2[m][s * 32 + q * 8];
            bf16x8 ha1 = *(const bf16x8*)&H2[m + 16][s * 32 + q * 8];
            macc0 = __builtin_amdgcn_mfma_f32_16x16x32_bf16(ha0, bfr, macc0, 0, 0, 0);
            macc1 = __builtin_amdgcn_mfma_f32_16x16x32_bf16(ha1, bfr, macc1, 0, 0, 0);
        }
        __syncthreads();   // H2 reads done before next half overwrites / epilogue
    }

    // epilogue: stage 32x64 f32 tile in LDS (all smem dead now), coalesced NT dump
    float* OS = (float*)smem;                     // [32][64], 8192 B
    float bc = bm2[colo];
#pragma unroll
    for (int r = 0; r < 4; r++) {
        OS[(q * 4 + r) * 64 + colo]        = macc0[r] + bc;
        OS[(q * 4 + r + 16) * 64 + colo]   = macc1[r] + bc;
    }
    __syncthreads();
#pragma unroll
    for (int it = 0; it < 2; ++it) {
        int idx = it * 256 + (int)threadIdx.x;    // 512 x 16B = 8192B
        int row = idx >> 4, seg = idx & 15;
        f32x4 v = *(const f32x4*)&OS[row * 64 + seg * 4];
        __builtin_nontemporal_store(v, (f32x4*)&out[(size_t)(row0 + row) * 64 + seg * 4]);
    }
}

extern "C" void kernel_launch(void* const* d_in, const int* in_sizes, int n_in,
                              void* d_out, int out_size, void* d_ws, size_t ws_size,
                              hipStream_t stream) {
    const float* x    = (const float*)d_in[0];
    const int*   src  = (const int*)d_in[1];
    const int*   dst  = (const int*)d_in[2];
    const float* w1   = (const float*)d_in[3];
    const float* b1   = (const float*)d_in[4];
    const float* w2   = (const float*)d_in[5];
    const float* b2   = (const float*)d_in[6];
    const float* wm1  = (const float*)d_in[7];
    const float* bm1  = (const float*)d_in[8];
    const float* wm2  = (const float*)d_in[9];
    const float* bm2  = (const float*)d_in[10];

    const int N = N_NODES;
    const int E = N_EDGES;

    char* p = (char*)d_ws;
    auto alloc = [&](size_t bytes) -> void* {
        void* r = (void*)p;
        p += (bytes + 255) & ~(size_t)255;
        return r;
    };
    int*   gcntA   = (int*)alloc((NBUCK + 1) * 4);   // contiguous with gcntB: one memset
    int*   gcntB   = (int*)alloc((NBUCK + 1) * 4);
    int*   gbaseA  = (int*)alloc((NBUCK + 1) * 4);
    int*   gbaseB  = (int*)alloc((NBUCK + 1) * 4);
    int*   gcurA   = (int*)alloc((NBUCK + 1) * 4);
    int*   gcurB   = (int*)alloc((NBUCK + 1) * 4);
    int*   blkA    = (int*)alloc((size_t)NCHUNK * NBUCK * 4);   // per-block histograms
    int*   blkB    = (int*)alloc((size_t)NCHUNK * NBUCK * 4);
    int*   offsets = (int*)alloc((size_t)(N + 1) * 4);
    float* out_norm = (float*)alloc((size_t)N * 4);
    float* in_norm  = (float*)alloc((size_t)N * 4);
    int*   esrc     = (int*)alloc((size_t)E * 4);
    unsigned int* bufA = (unsigned int*)alloc((size_t)N * 128 * 2);  // xs
    unsigned int* bufB = (unsigned int*)alloc((size_t)N * 128 * 2);  // pairs (build only)
    unsigned int* bufC = (unsigned int*)alloc((size_t)N * 128 * 2);  // keysB, then h1
    unsigned short* wt1  = (unsigned short*)alloc(128 * 128 * 2);
    unsigned short* wt2  = (unsigned short*)alloc(128 * 128 * 2);
    unsigned short* wtm1 = (unsigned short*)alloc(256 * 128 * 2);
    unsigned short* wtm2 = (unsigned short*)alloc(64 * 256 * 2);
    (void)ws_size; (void)n_in; (void)in_sizes; (void)out_size;

    unsigned*       pairs = (unsigned*)bufB;       // packed (dloc<<17|src), dead after csr
    unsigned short* keysB = (unsigned short*)bufC; // bucket-local src ids, dead after count

    (void)hipMemsetAsync(gcntA, 0, (size_t)((char*)gcntB - (char*)gcntA) + NBUCK * 4, stream);

    const int TB = 256;
    // CSR build via two-level LDS counting sort (no per-edge global atomics)
    k_hist2<<<dim3(NCHUNK), dim3(TB), 0, stream>>>(src, dst, gcntA, gcntB, blkA, blkB, E);
    k_scan_coarse<<<dim3(1), dim3(512), 0, stream>>>(gcntA, gcntB, gbaseA, gbaseB,
                                                     gcurA, gcurB, offsets);
    k_scatter<<<dim3(NCHUNK), dim3(TB), 0, stream>>>(src, dst, gcurA, gcurB, blkA, blkB,
                                                     pairs, keysB, E);
    // per-bucket CSR + in-LDS canonical segment sort (bit-deterministic esrc)
    k_csr_sort<<<dim3(NBUCK), dim3(512), 0, stream>>>(pairs, gbaseA, offsets, in_norm, esrc);
    // out_norm from src counts + xs = bf16(x * out_norm) + all weight transposes
    k_count_scale<<<dim3(NBUCK), dim3(512), 0, stream>>>(
        keysB, gbaseB, (const float4*)x, out_norm, (uint2*)bufA,
        w1, w2, wm1, wm2, wt1, wt2, wtm1, wtm2);

    // conv1: fused aggregate + gemm(w1) + relu + fold out_norm (bufA -> bufC)
    k_conv<<<dim3(N / 32), dim3(TB), 0, stream>>>(
        offsets, esrc, (const uint4*)bufA, in_norm, wt1, b1, out_norm,
        (unsigned short*)bufC, N);

    // conv2 + MLP: fused aggregate + gemm(w2) + mlp1 + mlp2 (bufC -> d_out)
    k_conv2_mlp<<<dim3(N / 32), dim3(TB), 0, stream>>>(
        offsets, esrc, (const uint4*)bufC, in_norm, wt2, b2, wtm1, bm1, wtm2, bm2,
        (float*)d_out, N);
}